// Round 1
// baseline (81084.656 us; speedup 1.0000x reference)
//
#include <hip/hip_runtime.h>

// Problem constants (fixed by harness inputs)
#define BATCH 128
#define NSAMP 4
#define BN    512        // BATCH*NSAMP
#define HID   512
#define EMBD  512
#define VOC   512
#define TLEN  100
#define MLEN  256
#define NGATE 2048       // 4*HID

#define NPART 8          // split-K partials for all in-loop GEMMs

// persistent kernel shape
#define NBLK  256
#define NTHR  512

// output flat offsets (FLOAT32 elements)
#define O_ZID     0L
#define O_ZSTATES 51200L
#define O_ZLP     26265600L
#define O_STEP    26266112L
#define O_ENT     26317312L
#define O_TOTAL   26317313L

// workspace offsets (floats) inside g_ws
#define OFF_H    0L          // [512][1024]
#define OFF_C    524288L     // [512][1024]
#define OFF_X    1048576L    // [512][512]
#define OFF_G    1310720L    // 8 x [512][2048]
#define OFF_Q    9699328L    // 8 x [512][512]
#define OFF_CTX  11796480L   // [512][512]
#define OFF_O2   12058624L   // 8 x [512][512]
#define OFF_LG   14155776L   // 8 x [512][512]
#define OFF_YR   16252928L   // [512][512]
#define OFF_BG   16515072L   // [2][2048]
#define OFF_ENT  16519168L   // [128]
#define OFF_SLP  16519296L   // [100*512]
#define WS_FLOATS 16570496L

#define GPSTRIDE 1048576L    // 512*2048 gate-partial stride
#define SPSTRIDE 262144L     // 512*512 small-partial stride

__device__ float g_ws[WS_FLOATS];
__device__ int   g_ids[TLEN * BN];
__device__ unsigned bar_cnt;   // zero-init
__device__ unsigned bar_gen;   // zero-init

// ---------------- device-scope grid barrier (256 co-resident blocks) ----------------
__device__ __forceinline__ void gsync() {
  __syncthreads();                       // drains vmcnt/lgkmcnt for whole block
  if (threadIdx.x == 0) {
    __threadfence();                     // agent release: L2 writeback
    unsigned g = __hip_atomic_load(&bar_gen, __ATOMIC_RELAXED, __HIP_MEMORY_SCOPE_AGENT);
    unsigned a = __hip_atomic_fetch_add(&bar_cnt, 1u, __ATOMIC_ACQ_REL, __HIP_MEMORY_SCOPE_AGENT);
    if (a == (unsigned)(NBLK - 1)) {
      __hip_atomic_store(&bar_cnt, 0u, __ATOMIC_RELAXED, __HIP_MEMORY_SCOPE_AGENT);
      __hip_atomic_store(&bar_gen, g + 1u, __ATOMIC_RELEASE, __HIP_MEMORY_SCOPE_AGENT);
    } else {
      while (__hip_atomic_load(&bar_gen, __ATOMIC_RELAXED, __HIP_MEMORY_SCOPE_AGENT) == g)
        __builtin_amdgcn_s_sleep(2);
    }
    __threadfence();                     // agent acquire: invalidate L1/L2
  }
  __syncthreads();
}

// ---------------- threefry2x32 (JAX-exact, 20 rounds) ----------------
__device__ __forceinline__ unsigned rotl32(unsigned x, int r) {
  return (x << r) | (x >> (32 - r));
}
__device__ __forceinline__ void threefry2x32(unsigned k0, unsigned k1,
                                             unsigned& x0, unsigned& x1) {
  unsigned k2 = k0 ^ k1 ^ 0x1BD11BDAu;
#define TF_R(r) { x0 += x1; x1 = rotl32(x1, r); x1 ^= x0; }
  x0 += k0; x1 += k1;
  TF_R(13) TF_R(15) TF_R(26) TF_R(6)
  x0 += k1; x1 += k2 + 1u;
  TF_R(17) TF_R(29) TF_R(16) TF_R(24)
  x0 += k2; x1 += k0 + 2u;
  TF_R(13) TF_R(15) TF_R(26) TF_R(6)
  x0 += k0; x1 += k1 + 3u;
  TF_R(17) TF_R(29) TF_R(16) TF_R(24)
  x0 += k1; x1 += k2 + 4u;
  TF_R(13) TF_R(15) TF_R(26) TF_R(6)
  x0 += k2; x1 += k0 + 5u;
#undef TF_R
}

__device__ __forceinline__ float gumbel_from_bits(unsigned bits) {
  unsigned fb = (bits >> 9) | 0x3F800000u;
  float f = __uint_as_float(fb) - 1.0f;          // [0,1)
  const float TINY = 1.17549435e-38f;
  float u = fmaxf(f + TINY, TINY);
  return -logf(-logf(u));
}

// XLA-style logistic: 0.5 + 0.5*tanh(0.5*x)
__device__ __forceinline__ float sigf(float x) {
  return 0.5f + 0.5f * tanhf(0.5f * x);
}

__device__ __forceinline__ float4 add4(float4 a, float4 b) {
  a.x += b.x; a.y += b.y; a.z += b.z; a.w += b.w; return a;
}

// ---------------- wave-level split-K GEMM worker: 64x64 tile, 8x8 micro, BK=16 ----
// Bit-identical to the old gemmsk 64-thread block (same per-element k order).
// S: per-wave LDS slice (2048 floats). All waves of the block call with the same Kc.
__device__ __forceinline__ void gemm64_wave(
    float* __restrict__ S, int lane,
    int m0, int n0, int kp, int Kc,
    long offA1, int lda1, int P1, long sP1,
    const float* __restrict__ B1, int ldb1, int K1,
    long offA2, int lda2,
    const float* __restrict__ B2, int ldb2,
    const float* __restrict__ biasExt, long biasOff,
    long offC, int ldc)
{
  float* As = S;
  float* Bs = S + 1024;
  int kbase = kp * Kc;
  const float* A; const float* B; int lda, ldb, P; long sP;
  if (kbase < K1) {
    A = g_ws + offA1; B = B1; lda = lda1; ldb = ldb1; P = P1; sP = sP1;
  } else {
    A = g_ws + offA2; B = B2; lda = lda2; ldb = ldb2; P = 1; sP = 0;
    kbase -= K1;
  }

  const int tm = lane >> 3, tn = lane & 7;
  float acc[8][8];
#pragma unroll
  for (int i = 0; i < 8; ++i)
#pragma unroll
    for (int j = 0; j < 8; ++j) acc[i][j] = 0.f;

  for (int k0 = 0; k0 < Kc; k0 += 16) {
    const int kg = kbase + k0;
    const float* pa = A + (size_t)(m0 + lane) * lda + kg;
    float4 a0, a1, a2, a3;
    {
      const float4* q4 = (const float4*)pa;
      a0 = q4[0]; a1 = q4[1]; a2 = q4[2]; a3 = q4[3];
      for (int p = 1; p < P; ++p) {
        const float4* r4 = (const float4*)(pa + (size_t)p * sP);
        a0 = add4(a0, r4[0]); a1 = add4(a1, r4[1]);
        a2 = add4(a2, r4[2]); a3 = add4(a3, r4[3]);
      }
    }
    const float4* pb = (const float4*)(B + (size_t)(n0 + lane) * ldb + kg);
    float4 b0 = pb[0], b1 = pb[1], b2 = pb[2], b3 = pb[3];

    __syncthreads();
    As[ 0*64+lane]=a0.x; As[ 1*64+lane]=a0.y; As[ 2*64+lane]=a0.z; As[ 3*64+lane]=a0.w;
    As[ 4*64+lane]=a1.x; As[ 5*64+lane]=a1.y; As[ 6*64+lane]=a1.z; As[ 7*64+lane]=a1.w;
    As[ 8*64+lane]=a2.x; As[ 9*64+lane]=a2.y; As[10*64+lane]=a2.z; As[11*64+lane]=a2.w;
    As[12*64+lane]=a3.x; As[13*64+lane]=a3.y; As[14*64+lane]=a3.z; As[15*64+lane]=a3.w;
    Bs[ 0*64+lane]=b0.x; Bs[ 1*64+lane]=b0.y; Bs[ 2*64+lane]=b0.z; Bs[ 3*64+lane]=b0.w;
    Bs[ 4*64+lane]=b1.x; Bs[ 5*64+lane]=b1.y; Bs[ 6*64+lane]=b1.z; Bs[ 7*64+lane]=b1.w;
    Bs[ 8*64+lane]=b2.x; Bs[ 9*64+lane]=b2.y; Bs[10*64+lane]=b2.z; Bs[11*64+lane]=b2.w;
    Bs[12*64+lane]=b3.x; Bs[13*64+lane]=b3.y; Bs[14*64+lane]=b3.z; Bs[15*64+lane]=b3.w;
    __syncthreads();

#pragma unroll
    for (int k = 0; k < 16; ++k) {
      float av[8], bv[8];
      *(float4*)&av[0] = *(const float4*)&As[k*64 + tm*8];
      *(float4*)&av[4] = *(const float4*)&As[k*64 + tm*8 + 4];
      *(float4*)&bv[0] = *(const float4*)&Bs[k*64 + tn*8];
      *(float4*)&bv[4] = *(const float4*)&Bs[k*64 + tn*8 + 4];
#pragma unroll
      for (int i = 0; i < 8; ++i)
#pragma unroll
        for (int j = 0; j < 8; ++j)
          acc[i][j] += av[i] * bv[j];
    }
  }

  float* C = g_ws + offC + (size_t)kp * 512 * (size_t)ldc;
  const float* bias = nullptr;
  if (kp == 0)
    bias = biasExt ? biasExt : (biasOff >= 0 ? g_ws + biasOff : nullptr);
#pragma unroll
  for (int i = 0; i < 8; ++i) {
    const int row = m0 + tm * 8 + i;
    const int col = n0 + tn * 8;
    float4 o0, o1;
    o0.x = acc[i][0]; o0.y = acc[i][1]; o0.z = acc[i][2]; o0.w = acc[i][3];
    o1.x = acc[i][4]; o1.y = acc[i][5]; o1.z = acc[i][6]; o1.w = acc[i][7];
    if (bias) {
      o0.x += bias[col];     o0.y += bias[col + 1];
      o0.z += bias[col + 2]; o0.w += bias[col + 3];
      o1.x += bias[col + 4]; o1.y += bias[col + 5];
      o1.z += bias[col + 6]; o1.w += bias[col + 7];
    }
    *(float4*)(C + (size_t)row * ldc + col)     = o0;
    *(float4*)(C + (size_t)row * ldc + col + 4) = o1;
  }
}

// ---------------- wave-level split-K GEMM worker: 32x32 tile, 4x4 micro, BK=16 ----
// Per-element k order identical to 64x64 version -> bit-identical outputs.
__device__ __forceinline__ void gemm32_wave(
    float* __restrict__ S, int lane,
    int m0, int n0, int kp, int Kc,
    long offA1, int lda1, int P1, long sP1,
    const float* __restrict__ B1, int ldb1, int K1,
    long offA2, int lda2,
    const float* __restrict__ B2, int ldb2,
    const float* __restrict__ biasExt, long biasOff,
    long offC, int ldc)
{
  float* As = S;
  float* Bs = S + 512;
  int kbase = kp * Kc;
  const float* A; const float* B; int lda, ldb, P; long sP;
  if (kbase < K1) {
    A = g_ws + offA1; B = B1; lda = lda1; ldb = ldb1; P = P1; sP = sP1;
  } else {
    A = g_ws + offA2; B = B2; lda = lda2; ldb = ldb2; P = 1; sP = 0;
    kbase -= K1;
  }

  const int r  = lane & 31;
  const int ko = (lane >> 5) * 8;
  const int tm = lane >> 3, tn = lane & 7;
  float acc[4][4];
#pragma unroll
  for (int i = 0; i < 4; ++i)
#pragma unroll
    for (int j = 0; j < 4; ++j) acc[i][j] = 0.f;

  for (int k0 = 0; k0 < Kc; k0 += 16) {
    const int kg = kbase + k0;
    const float* pa = A + (size_t)(m0 + r) * lda + kg + ko;
    float4 a0, a1;
    {
      const float4* q4 = (const float4*)pa;
      a0 = q4[0]; a1 = q4[1];
      for (int p = 1; p < P; ++p) {
        const float4* r4 = (const float4*)(pa + (size_t)p * sP);
        a0 = add4(a0, r4[0]); a1 = add4(a1, r4[1]);
      }
    }
    const float4* pb = (const float4*)(B + (size_t)(n0 + r) * ldb + kg + ko);
    float4 b0 = pb[0], b1 = pb[1];

    __syncthreads();
    As[(ko+0)*32+r]=a0.x; As[(ko+1)*32+r]=a0.y; As[(ko+2)*32+r]=a0.z; As[(ko+3)*32+r]=a0.w;
    As[(ko+4)*32+r]=a1.x; As[(ko+5)*32+r]=a1.y; As[(ko+6)*32+r]=a1.z; As[(ko+7)*32+r]=a1.w;
    Bs[(ko+0)*32+r]=b0.x; Bs[(ko+1)*32+r]=b0.y; Bs[(ko+2)*32+r]=b0.z; Bs[(ko+3)*32+r]=b0.w;
    Bs[(ko+4)*32+r]=b1.x; Bs[(ko+5)*32+r]=b1.y; Bs[(ko+6)*32+r]=b1.z; Bs[(ko+7)*32+r]=b1.w;
    __syncthreads();

#pragma unroll
    for (int k = 0; k < 16; ++k) {
      float4 av = *(const float4*)&As[k*32 + tm*4];
      float4 bv = *(const float4*)&Bs[k*32 + tn*4];
      acc[0][0] += av.x*bv.x; acc[0][1] += av.x*bv.y; acc[0][2] += av.x*bv.z; acc[0][3] += av.x*bv.w;
      acc[1][0] += av.y*bv.x; acc[1][1] += av.y*bv.y; acc[1][2] += av.y*bv.z; acc[1][3] += av.y*bv.w;
      acc[2][0] += av.z*bv.x; acc[2][1] += av.z*bv.y; acc[2][2] += av.z*bv.z; acc[2][3] += av.z*bv.w;
      acc[3][0] += av.w*bv.x; acc[3][1] += av.w*bv.y; acc[3][2] += av.w*bv.z; acc[3][3] += av.w*bv.w;
    }
  }

  float* C = g_ws + offC + (size_t)kp * 512 * (size_t)ldc;
  const float* bias = nullptr;
  if (kp == 0)
    bias = biasExt ? biasExt : (biasOff >= 0 ? g_ws + biasOff : nullptr);
#pragma unroll
  for (int i = 0; i < 4; ++i) {
    const int row = m0 + tm * 4 + i;
    const int col = n0 + tn * 4;
    float4 o;
    o.x = acc[i][0]; o.y = acc[i][1]; o.z = acc[i][2]; o.w = acc[i][3];
    if (bias) {
      o.x += bias[col];     o.y += bias[col + 1];
      o.z += bias[col + 2]; o.w += bias[col + 3];
    }
    *(float4*)(C + (size_t)row * ldc + col) = o;
  }
}

// ---------------- LSTM cell elementwise; sums NPART gate partials ----------------
__device__ __forceinline__ void cell_phase(long hoff, long coff) {
  for (int idx = blockIdx.x * NTHR + threadIdx.x; idx < 262144; idx += NBLK * NTHR) {
    int rr = idx >> 9, j = idx & 511;
    float gi = 0.f, gf = 0.f, gg = 0.f, go = 0.f;
    const size_t rb = (size_t)rr * NGATE;
#pragma unroll
    for (int p = 0; p < NPART; ++p) {
      const float* gr = g_ws + OFF_G + (size_t)p * GPSTRIDE + rb;
      gi += gr[j]; gf += gr[512 + j]; gg += gr[1024 + j]; go += gr[1536 + j];
    }
    float* h = g_ws + hoff;
    float* c = g_ws + coff;
    float cold = c[(size_t)rr * 1024 + j];
    float cn = sigf(gf) * cold + sigf(gi) * tanhf(gg);
    float hn = sigf(go) * tanhf(cn);
    c[(size_t)rr * 1024 + j] = cn;
    h[(size_t)rr * 1024 + j] = hn;
  }
}

// ---------------- attention phase: blocks 0..127, tid<256 active ----------------
__device__ __forceinline__ void attn_phase(const float* __restrict__ kv,
                                           const void* __restrict__ kvm_raw,
                                           float* __restrict__ smem) {
  const int bb = blockIdx.x;
  if (bb >= 128) return;
  float* qs  = smem;          // [4][512]
  float* scb = smem + 2048;   // [4][256]
  const int tid = threadIdx.x;
  const bool act = tid < 256;
  const int lane = tid & 63, wv = tid >> 6;
  float* ctx = g_ws + OFF_CTX;
  const float* kvb = kv + (size_t)bb * MLEN * HID;
  const unsigned* w32 = (const unsigned*)kvm_raw;
  const unsigned char* u8 = (const unsigned char*)kvm_raw;
  if (act) {
#pragma unroll
    for (int s = 0; s < 4; ++s) {
      float q0 = 0.f, q1 = 0.f;
      const size_t base = (size_t)(bb * 4 + s) * HID + tid;
#pragma unroll
      for (int p = 0; p < NPART; ++p) {
        q0 += g_ws[OFF_Q + (size_t)p * SPSTRIDE + base];
        q1 += g_ws[OFF_Q + (size_t)p * SPSTRIDE + base + 256];
      }
      qs[s*512 + tid] = q0; qs[s*512 + tid + 256] = q1;
    }
  }
  __syncthreads();
  if (act) {
    const bool u8mode = (w32[0] == 0x01010101u);
    for (int m = wv; m < MLEN; m += 4) {
      const float* kr = kvb + (size_t)m * HID;
      float a0 = 0.f, a1 = 0.f, a2 = 0.f, a3 = 0.f;
      for (int d = lane; d < HID; d += 64) {
        float kvv = kr[d];
        a0 += qs[0*512 + d] * kvv; a1 += qs[1*512 + d] * kvv;
        a2 += qs[2*512 + d] * kvv; a3 += qs[3*512 + d] * kvv;
      }
#pragma unroll
      for (int off = 32; off > 0; off >>= 1) {
        a0 += __shfl_down(a0, off); a1 += __shfl_down(a1, off);
        a2 += __shfl_down(a2, off); a3 += __shfl_down(a3, off);
      }
      if (lane == 0) {
        bool on = u8mode ? (u8[bb * MLEN + m] != 0) : (w32[bb * MLEN + m] != 0u);
        float madd = on ? 0.0f : -1e9f;
        scb[0*256+m] = a0 + madd; scb[1*256+m] = a1 + madd;
        scb[2*256+m] = a2 + madd; scb[3*256+m] = a3 + madd;
      }
    }
  }
  __syncthreads();
  if (act) {
    const int s = wv;
    float mx = -3.4e38f;
    for (int m = lane; m < MLEN; m += 64) mx = fmaxf(mx, scb[s*256+m]);
#pragma unroll
    for (int off = 32; off > 0; off >>= 1) mx = fmaxf(mx, __shfl_xor(mx, off));
    float sum = 0.f;
    for (int m = lane; m < MLEN; m += 64) {
      float e = expf(scb[s*256+m] - mx);
      scb[s*256+m] = e; sum += e;
    }
#pragma unroll
    for (int off = 32; off > 0; off >>= 1) sum += __shfl_xor(sum, off);
    for (int m = lane; m < MLEN; m += 64) scb[s*256+m] = scb[s*256+m] / sum;
  }
  __syncthreads();
  if (act) {
    float c00=0,c01=0,c10=0,c11=0,c20=0,c21=0,c30=0,c31=0;
    for (int m = 0; m < MLEN; ++m) {
      float k0v = kvb[(size_t)m * HID + tid];
      float k1v = kvb[(size_t)m * HID + tid + 256];
      float p0 = scb[0*256+m], p1 = scb[1*256+m], p2 = scb[2*256+m], p3 = scb[3*256+m];
      c00 += p0 * k0v; c01 += p0 * k1v;
      c10 += p1 * k0v; c11 += p1 * k1v;
      c20 += p2 * k0v; c21 += p2 * k1v;
      c30 += p3 * k0v; c31 += p3 * k1v;
    }
    ctx[(size_t)(bb*4 + 0) * HID + tid] = c00; ctx[(size_t)(bb*4 + 0) * HID + tid + 256] = c01;
    ctx[(size_t)(bb*4 + 1) * HID + tid] = c10; ctx[(size_t)(bb*4 + 1) * HID + tid + 256] = c11;
    ctx[(size_t)(bb*4 + 2) * HID + tid] = c20; ctx[(size_t)(bb*4 + 2) * HID + tid + 256] = c21;
    ctx[(size_t)(bb*4 + 3) * HID + tid] = c30; ctx[(size_t)(bb*4 + 3) * HID + tid + 256] = c31;
  }
}

// ---------------- sampling phase: 2 rows per block (sub-block of 256 threads) ----
__device__ __forceinline__ void sample_phase(const float* __restrict__ emb, int t,
                                             float* __restrict__ smem) {
  float* rz = smem;                 // [2][256]
  float* rl = smem + 512;           // [2][256]
  int*   ri = (int*)(smem + 1024);  // [2][256]
  const int sub  = threadIdx.x >> 8;
  const int stid = threadIdx.x & 255;
  const int row  = blockIdx.x * 2 + sub;
  float* rzs = rz + sub * 256;
  float* rls = rl + sub * 256;
  int*   ris = ri + sub * 256;
  float* xbuf = g_ws + OFF_X;

  unsigned fk0 = 0u, fk1 = (unsigned)t;
  threefry2x32(0u, 42u, fk0, fk1);

  float l[2], gv[2];
#pragma unroll
  for (int j = 0; j < 2; ++j) {
    int v = stid + j * 256;
    unsigned c0 = 0u, c1 = (unsigned)(row * VOC + v);
    threefry2x32(fk0, fk1, c0, c1);
    gv[j] = gumbel_from_bits(c0 ^ c1);
    float lv = 0.f;
    const size_t base = (size_t)row * VOC + v;
#pragma unroll
    for (int p = 0; p < NPART; ++p)
      lv += g_ws[OFF_LG + (size_t)p * SPSTRIDE + base];
    l[j] = lv;
  }

  float z0 = l[0] + gv[0], z1 = l[1] + gv[1];
  float bz; int bi; float bl;
  if (z1 > z0) { bz = z1; bi = stid + 256; bl = l[1]; }
  else         { bz = z0; bi = stid;       bl = l[0]; }
  rzs[stid] = bz; ris[stid] = bi; rls[stid] = bl;
  __syncthreads();
  for (int s = 128; s > 0; s >>= 1) {
    if (stid < s) {
      float oz = rzs[stid + s]; int oi = ris[stid + s];
      if (oz > rzs[stid] || (oz == rzs[stid] && oi < ris[stid])) {
        rzs[stid] = oz; ris[stid] = oi; rls[stid] = rls[stid + s];
      }
    }
    __syncthreads();
  }
  const int sidx = ris[0];
  const float l_at = rls[0];
  __syncthreads();

  rzs[stid] = fmaxf(l[0], l[1]);
  __syncthreads();
  for (int s = 128; s > 0; s >>= 1) {
    if (stid < s) rzs[stid] = fmaxf(rzs[stid], rzs[stid + s]);
    __syncthreads();
  }
  const float m = rzs[0];
  __syncthreads();

  float d0 = l[0] - m, d1 = l[1] - m;
  float e0 = expf(d0), e1 = expf(d1);
  rzs[stid] = e0 + e1;
  rls[stid] = e0 * d0 + e1 * d1;
  __syncthreads();
  for (int s = 128; s > 0; s >>= 1) {
    if (stid < s) { rzs[stid] += rzs[stid + s]; rls[stid] += rls[stid + s]; }
    __syncthreads();
  }
  if (stid == 0) {
    float S = rzs[0], W = rls[0];
    float logS = logf(S);
    g_ids[t * BN + row] = sidx;
    g_ws[OFF_SLP + t * BN + row] = (l_at - m) - logS;
    atomicAdd(&g_ws[OFF_ENT + t], logS - W / S);
  }
  const float* er = emb + (size_t)sidx * EMBD;
  xbuf[(size_t)row * EMBD + stid]       = er[stid];
  xbuf[(size_t)row * EMBD + stid + 256] = er[stid + 256];
}

// ---------------- THE persistent kernel: whole T-loop, 9 grid barriers/step ------
__global__ __launch_bounds__(NTHR, 2) void persist(
    const float* __restrict__ kv, const void* __restrict__ kvm,
    const float* __restrict__ emb,
    const float* __restrict__ W_ih, const float* __restrict__ W_hh,
    const float* __restrict__ W_attn, const float* __restrict__ W_cproj,
    const float* __restrict__ b_cproj, const float* __restrict__ W_out,
    const float* __restrict__ b_out)
{
  __shared__ __align__(16) float smem[16384];   // 64 KiB
  const int tid  = threadIdx.x;
  const int w    = tid >> 6;
  const int lane = tid & 63;
  float* S = smem + w * 2048;                   // per-wave GEMM slice

  // stable tile ownership (XCD-local weight slices; blockIdx%8 ~ XCD)
  const int xb = blockIdx.x & 7, jb = blockIdx.x >> 3;
  const int g_nt = xb * 4 + (jb >> 3), g_mt = jb & 7;    // gates: 32 n x 8 m
  const int s_nt = xb * 2 + (jb >> 4), s_mt = jb & 15;   // small: 16 n x 16 m
  const size_t WL = (size_t)NGATE * HID;

#pragma unroll 1
  for (int t = 0; t < TLEN; ++t) {
    // layer 0 gates (identical numerics to old gemmsk launch)
    gemm64_wave(S, lane, g_mt * 64, g_nt * 64, w, 128,
                OFF_X, 512, 1, 0L, W_ih, 512, 512,
                OFF_H, 1024, W_hh, 512,
                nullptr, OFF_BG, OFF_G, NGATE);
    gsync();
    cell_phase(OFF_H, OFF_C);
    gsync();
    // layer 1 gates
    gemm64_wave(S, lane, g_mt * 64, g_nt * 64, w, 128,
                OFF_H, 1024, 1, 0L, W_ih + WL, 512, 512,
                OFF_H + 512, 1024, W_hh + WL, 512,
                nullptr, OFF_BG + NGATE, OFF_G, NGATE);
    gsync();
    cell_phase(OFF_H + 512, OFF_C + 512);
    gsync();
    // q = h1 @ W_attn^T  (Kc=64 over K=512)
    gemm32_wave(S, lane, s_mt * 32, s_nt * 32, w, 64,
                OFF_H + 512, 1024, 1, 0L, W_attn, 512, 512,
                0L, 0, nullptr, 0,
                nullptr, -1L, OFF_Q, 512);
    gsync();
    attn_phase(kv, kvm, smem);
    gsync();
    // out2 = [h1|ctx] @ W_cproj^T + b  (Kc=128 over K=1024)
    gemm32_wave(S, lane, s_mt * 32, s_nt * 32, w, 128,
                OFF_H + 512, 1024, 1, 0L, W_cproj, 1024, 512,
                OFF_CTX, 512, W_cproj + 512, 1024,
                b_cproj, -1L, OFF_O2, 512);
    gsync();
    // logits = out2 @ W_out^T + b  (A sums 8 out2 partials; Kc=64)
    gemm32_wave(S, lane, s_mt * 32, s_nt * 32, w, 64,
                OFF_O2, 512, NPART, SPSTRIDE, W_out, 512, 512,
                0L, 0, nullptr, 0,
                b_out, -1L, OFF_LG, 512);
    gsync();
    sample_phase(emb, t, smem);
    gsync();
  }
}

// ---------------- single-pass GEMM (init h0/c0 only, unchanged) ----------------
__global__ __launch_bounds__(256) void gemm2(
    long offA1, int lda1,
    const float* __restrict__ B1, int ldb1, int K1,
    long offA2, int lda2,
    const float* __restrict__ B2, int ldb2, int K2,
    const float* __restrict__ biasExt, long biasOff,
    long offC, int ldc)
{
  __shared__ float As[16][68];
  __shared__ float Bs[16][68];
  const int tid = threadIdx.x;
  const int tx  = tid & 15;
  const int ty  = tid >> 4;
  const int ldr = tid >> 2;
  const int ldk = (tid & 3) << 2;
  const int m0 = blockIdx.y * 64;
  const int n0 = blockIdx.x * 64;
  float acc[4][4] = {{0.f}};

  for (int seg = 0; seg < 2; ++seg) {
    const float* A = g_ws + (seg ? offA2 : offA1);
    const float* B = seg ? B2 : B1;
    const int lda = seg ? lda2 : lda1;
    const int ldb = seg ? ldb2 : ldb1;
    const int K   = seg ? K2  : K1;
    for (int k0 = 0; k0 < K; k0 += 16) {
      float4 av = *(const float4*)(A + (size_t)(m0 + ldr) * lda + k0 + ldk);
      float4 bv = *(const float4*)(B + (size_t)(n0 + ldr) * ldb + k0 + ldk);
      __syncthreads();
      As[ldk + 0][ldr] = av.x; As[ldk + 1][ldr] = av.y;
      As[ldk + 2][ldr] = av.z; As[ldk + 3][ldr] = av.w;
      Bs[ldk + 0][ldr] = bv.x; Bs[ldk + 1][ldr] = bv.y;
      Bs[ldk + 2][ldr] = bv.z; Bs[ldk + 3][ldr] = bv.w;
      __syncthreads();
#pragma unroll
      for (int k = 0; k < 16; ++k) {
        float4 a = *(const float4*)&As[k][ty * 4];
        float4 b = *(const float4*)&Bs[k][tx * 4];
        acc[0][0] += a.x * b.x; acc[0][1] += a.x * b.y; acc[0][2] += a.x * b.z; acc[0][3] += a.x * b.w;
        acc[1][0] += a.y * b.x; acc[1][1] += a.y * b.y; acc[1][2] += a.y * b.z; acc[1][3] += a.y * b.w;
        acc[2][0] += a.z * b.x; acc[2][1] += a.z * b.y; acc[2][2] += a.z * b.z; acc[2][3] += a.z * b.w;
        acc[3][0] += a.w * b.x; acc[3][1] += a.w * b.y; acc[3][2] += a.w * b.z; acc[3][3] += a.w * b.w;
      }
    }
  }
  const float* bias = biasExt ? biasExt : (biasOff >= 0 ? g_ws + biasOff : nullptr);
  float* C = g_ws + offC;
#pragma unroll
  for (int i = 0; i < 4; ++i) {
    int row = m0 + ty * 4 + i;
    int col = n0 + tx * 4;
    float4 o;
    o.x = acc[i][0]; o.y = acc[i][1]; o.z = acc[i][2]; o.w = acc[i][3];
    if (bias) {
      o.x += bias[col]; o.y += bias[col + 1]; o.z += bias[col + 2]; o.w += bias[col + 3];
    }
    *(float4*)(C + (size_t)row * ldc + col) = o;
  }
}

// ---------------- init ----------------
__global__ __launch_bounds__(256) void init_misc(
    const float* __restrict__ y, const float* __restrict__ emb,
    const float* __restrict__ b_ih, const float* __restrict__ b_hh)
{
  int gid = blockIdx.x * 256 + threadIdx.x;
  int r = gid >> 9, col = gid & 511;
  g_ws[OFF_YR + gid] = y[(size_t)(r >> 2) * HID + col];
  g_ws[OFF_X + gid]  = emb[(size_t)(VOC - 1) * EMBD + col];
  if (gid < 2 * NGATE) g_ws[OFF_BG + gid] = b_ih[gid] + b_hh[gid];
  if (gid < 128) g_ws[OFF_ENT + gid] = 0.0f;
}

// ---------------- SINGLE output writer (f32) ----------------
__global__ __launch_bounds__(256) void write_out(
    const float* __restrict__ emb, const float* __restrict__ zmask,
    float* __restrict__ out)
{
  long i = (long)blockIdx.x * 256 + threadIdx.x;
  const long stride = (long)gridDim.x * 256;
  for (; i < O_TOTAL; i += stride) {
    float v;
    if (i < O_ZSTATES) {
      int bs = (int)(i / TLEN), t = (int)(i % TLEN);
      v = (float)g_ids[t * BN + bs];
    } else if (i < O_ZLP) {
      long j = i - O_ZSTATES;
      int e = (int)(j & 511);
      int bst = (int)(j >> 9);
      int bs = bst / TLEN, t = bst % TLEN;
      v = emb[(size_t)g_ids[t * BN + bs] * EMBD + e];
    } else if (i < O_STEP) {
      int bs = (int)(i - O_ZLP);
      int b = bs >> 2;
      float acc = 0.f;
      for (int t = 0; t < TLEN; ++t)
        acc += g_ws[OFF_SLP + t * BN + bs] * zmask[b * TLEN + t];
      v = acc;
    } else if (i < O_ENT) {
      long j = i - O_STEP;
      int bs = (int)(j / TLEN), t = (int)(j % TLEN);
      v = g_ws[OFF_SLP + t * BN + bs];
    } else {
      float e = 0.f;
      for (int t = 0; t < TLEN; ++t) e += g_ws[OFF_ENT + t];
      v = e / (float)(BN * TLEN);
    }
    out[i] = v;
  }
}

// ---------------- host ----------------
extern "C" void kernel_launch(void* const* d_in, const int* in_sizes, int n_in,
                              void* d_out, int out_size, void* d_ws, size_t ws_size,
                              hipStream_t stream) {
  (void)in_sizes; (void)n_in; (void)out_size; (void)d_ws; (void)ws_size;
  const float* y       = (const float*)d_in[0];
  const float* kv      = (const float*)d_in[1];
  const void*  kvm     = (const void*)d_in[2];
  const float* zmask   = (const float*)d_in[3];
  const float* emb     = (const float*)d_in[4];
  const float* W_h0    = (const float*)d_in[5];
  const float* b_h0    = (const float*)d_in[6];
  const float* W_c0    = (const float*)d_in[7];
  const float* b_c0    = (const float*)d_in[8];
  const float* W_ih    = (const float*)d_in[9];
  const float* W_hh    = (const float*)d_in[10];
  const float* b_ih    = (const float*)d_in[11];
  const float* b_hh    = (const float*)d_in[12];
  const float* W_attn  = (const float*)d_in[13];
  const float* W_cproj = (const float*)d_in[14];
  const float* b_cproj = (const float*)d_in[15];
  const float* W_out   = (const float*)d_in[16];
  const float* b_out   = (const float*)d_in[17];
  float* out = (float*)d_out;

  init_misc<<<1024, 256, 0, stream>>>(y, emb, b_ih, b_hh);

  // init h0 / c0 (outside loop)
  dim3 g_init(1024 / 64, 512 / 64);
  gemm2<<<g_init, 256, 0, stream>>>(OFF_YR, 512, W_h0, 512, 512,
                                    0L, 0, nullptr, 0, 0, b_h0, -1L, OFF_H, 1024);
  gemm2<<<g_init, 256, 0, stream>>>(OFF_YR, 512, W_c0, 512, 512,
                                    0L, 0, nullptr, 0, 0, b_c0, -1L, OFF_C, 1024);

  // the whole T=100 decode loop in ONE persistent kernel
  persist<<<NBLK, NTHR, 0, stream>>>(kv, kvm, emb, W_ih, W_hh,
                                     W_attn, W_cproj, b_cproj, W_out, b_out);

  int wblocks = (int)((O_TOTAL + 255L) / 256L);
  write_out<<<wblocks, 256, 0, stream>>>(emb, zmask, out);
}

// Round 2
// 25387.926 us; speedup vs baseline: 3.1938x; 3.1938x over previous
//
#include <hip/hip_runtime.h>

// Problem constants (fixed by harness inputs)
#define BATCH 128
#define NSAMP 4
#define BN    512        // BATCH*NSAMP
#define HID   512
#define EMBD  512
#define VOC   512
#define TLEN  100
#define MLEN  256
#define NGATE 2048       // 4*HID

#define NPART 8          // split-K partials for gate GEMMs

// output flat offsets (FLOAT32 elements)
#define O_ZID     0L
#define O_ZSTATES 51200L
#define O_ZLP     26265600L
#define O_STEP    26266112L
#define O_ENT     26317312L
#define O_TOTAL   26317313L

// workspace offsets (floats) inside g_ws
#define OFF_H    0L          // [512][1024]
#define OFF_C    524288L     // [512][1024]
#define OFF_X    1048576L    // [512][512]
#define OFF_G    1310720L    // 8 x [512][2048]
#define OFF_O2   12058624L   // [512][512] (single buffer now)
#define OFF_YR   16252928L   // [512][512]
#define OFF_BG   16515072L   // [2][2048]
#define OFF_ENT  16519168L   // [128]
#define OFF_SLP  16519296L   // [100*512]
#define WS_FLOATS 16570496L

#define GPSTRIDE 1048576L    // 512*2048 gate-partial stride

__device__ float g_ws[WS_FLOATS];
__device__ int   g_ids[TLEN * BN];

// ---------------- threefry2x32 (JAX-exact, 20 rounds) ----------------
__device__ __forceinline__ unsigned rotl32(unsigned x, int r) {
  return (x << r) | (x >> (32 - r));
}
__device__ __forceinline__ void threefry2x32(unsigned k0, unsigned k1,
                                             unsigned& x0, unsigned& x1) {
  unsigned k2 = k0 ^ k1 ^ 0x1BD11BDAu;
#define TF_R(r) { x0 += x1; x1 = rotl32(x1, r); x1 ^= x0; }
  x0 += k0; x1 += k1;
  TF_R(13) TF_R(15) TF_R(26) TF_R(6)
  x0 += k1; x1 += k2 + 1u;
  TF_R(17) TF_R(29) TF_R(16) TF_R(24)
  x0 += k2; x1 += k0 + 2u;
  TF_R(13) TF_R(15) TF_R(26) TF_R(6)
  x0 += k0; x1 += k1 + 3u;
  TF_R(17) TF_R(29) TF_R(16) TF_R(24)
  x0 += k1; x1 += k2 + 4u;
  TF_R(13) TF_R(15) TF_R(26) TF_R(6)
  x0 += k2; x1 += k0 + 5u;
#undef TF_R
}

__device__ __forceinline__ float gumbel_from_bits(unsigned bits) {
  unsigned fb = (bits >> 9) | 0x3F800000u;
  float f = __uint_as_float(fb) - 1.0f;          // [0,1)
  const float TINY = 1.17549435e-38f;
  float u = fmaxf(f + TINY, TINY);
  return -logf(-logf(u));
}

// XLA-style logistic: 0.5 + 0.5*tanh(0.5*x)
__device__ __forceinline__ float sigf(float x) {
  return 0.5f + 0.5f * tanhf(0.5f * x);
}

__device__ __forceinline__ float4 add4(float4 a, float4 b) {
  a.x += b.x; a.y += b.y; a.z += b.z; a.w += b.w; return a;
}

// ---------------- split-K fp32 GEMM: 64 threads, 64x64 tile, 8x8 micro, BK=16 ----
// (verbatim from the 23.3 ms baseline — gate GEMMs only now)
__global__ __launch_bounds__(64) void gemmsk(
    long offA1, int lda1, int P1, long strideP1,
    const float* __restrict__ B1, int ldb1, int K1,
    long offA2, int lda2,
    const float* __restrict__ B2, int ldb2,
    const float* __restrict__ biasExt, long biasOff,
    long offC, int ldc, int Kc)
{
  __shared__ float As[16][64];
  __shared__ float Bs[16][64];
  const int t  = threadIdx.x;
  const int tm = t >> 3;         // 0..7
  const int tn = t & 7;          // 0..7
  const int m0 = blockIdx.y * 64;
  const int n0 = blockIdx.x * 64;
  const int kp = blockIdx.z;

  int kbase = kp * Kc;
  const float* A; const float* B; int lda, ldb, P; long strideP;
  if (kbase < K1) {
    A = g_ws + offA1; B = B1; lda = lda1; ldb = ldb1; P = P1; strideP = strideP1;
  } else {
    A = g_ws + offA2; B = B2; lda = lda2; ldb = ldb2; P = 1; strideP = 0;
    kbase -= K1;
  }

  float acc[8][8];
#pragma unroll
  for (int i = 0; i < 8; ++i)
#pragma unroll
    for (int j = 0; j < 8; ++j) acc[i][j] = 0.f;

  for (int k0 = 0; k0 < Kc; k0 += 16) {
    const int kg = kbase + k0;
    const float* pa = A + (size_t)(m0 + t) * lda + kg;
    float4 a0, a1, a2, a3;
    {
      const float4* q4 = (const float4*)pa;
      a0 = q4[0]; a1 = q4[1]; a2 = q4[2]; a3 = q4[3];
      for (int p = 1; p < P; ++p) {
        const float4* r4 = (const float4*)(pa + (size_t)p * strideP);
        a0 = add4(a0, r4[0]); a1 = add4(a1, r4[1]);
        a2 = add4(a2, r4[2]); a3 = add4(a3, r4[3]);
      }
    }
    const float4* pb = (const float4*)(B + (size_t)(n0 + t) * ldb + kg);
    float4 b0 = pb[0], b1 = pb[1], b2 = pb[2], b3 = pb[3];

    __syncthreads();
    As[ 0][t] = a0.x; As[ 1][t] = a0.y; As[ 2][t] = a0.z; As[ 3][t] = a0.w;
    As[ 4][t] = a1.x; As[ 5][t] = a1.y; As[ 6][t] = a1.z; As[ 7][t] = a1.w;
    As[ 8][t] = a2.x; As[ 9][t] = a2.y; As[10][t] = a2.z; As[11][t] = a2.w;
    As[12][t] = a3.x; As[13][t] = a3.y; As[14][t] = a3.z; As[15][t] = a3.w;
    Bs[ 0][t] = b0.x; Bs[ 1][t] = b0.y; Bs[ 2][t] = b0.z; Bs[ 3][t] = b0.w;
    Bs[ 4][t] = b1.x; Bs[ 5][t] = b1.y; Bs[ 6][t] = b1.z; Bs[ 7][t] = b1.w;
    Bs[ 8][t] = b2.x; Bs[ 9][t] = b2.y; Bs[10][t] = b2.z; Bs[11][t] = b2.w;
    Bs[12][t] = b3.x; Bs[13][t] = b3.y; Bs[14][t] = b3.z; Bs[15][t] = b3.w;
    __syncthreads();

#pragma unroll
    for (int k = 0; k < 16; ++k) {
      float av[8], bv[8];
      *(float4*)&av[0] = *(const float4*)&As[k][tm * 8];
      *(float4*)&av[4] = *(const float4*)&As[k][tm * 8 + 4];
      *(float4*)&bv[0] = *(const float4*)&Bs[k][tn * 8];
      *(float4*)&bv[4] = *(const float4*)&Bs[k][tn * 8 + 4];
#pragma unroll
      for (int i = 0; i < 8; ++i)
#pragma unroll
        for (int j = 0; j < 8; ++j)
          acc[i][j] += av[i] * bv[j];
    }
  }

  const int Mtot = gridDim.y * 64;
  float* C = g_ws + offC + (size_t)kp * (size_t)Mtot * ldc;
  const float* bias = nullptr;
  if (kp == 0)
    bias = biasExt ? biasExt : (biasOff >= 0 ? g_ws + biasOff : nullptr);
#pragma unroll
  for (int i = 0; i < 8; ++i) {
    const int row = m0 + tm * 8 + i;
    const int col = n0 + tn * 8;
    float4 o0, o1;
    o0.x = acc[i][0]; o0.y = acc[i][1]; o0.z = acc[i][2]; o0.w = acc[i][3];
    o1.x = acc[i][4]; o1.y = acc[i][5]; o1.z = acc[i][6]; o1.w = acc[i][7];
    if (bias) {
      o0.x += bias[col];     o0.y += bias[col + 1];
      o0.z += bias[col + 2]; o0.w += bias[col + 3];
      o1.x += bias[col + 4]; o1.y += bias[col + 5];
      o1.z += bias[col + 6]; o1.w += bias[col + 7];
    }
    *(float4*)(C + (size_t)row * ldc + col)     = o0;
    *(float4*)(C + (size_t)row * ldc + col + 4) = o1;
  }
}

// ---------------- old single-pass GEMM (init h0/c0 only) ----------------
__global__ __launch_bounds__(256) void gemm2(
    long offA1, int lda1,
    const float* __restrict__ B1, int ldb1, int K1,
    long offA2, int lda2,
    const float* __restrict__ B2, int ldb2, int K2,
    const float* __restrict__ biasExt, long biasOff,
    long offC, int ldc)
{
  __shared__ float As[16][68];
  __shared__ float Bs[16][68];
  const int tid = threadIdx.x;
  const int tx  = tid & 15;
  const int ty  = tid >> 4;
  const int ldr = tid >> 2;
  const int ldk = (tid & 3) << 2;
  const int m0 = blockIdx.y * 64;
  const int n0 = blockIdx.x * 64;
  float acc[4][4] = {{0.f}};

  for (int seg = 0; seg < 2; ++seg) {
    const float* A = g_ws + (seg ? offA2 : offA1);
    const float* B = seg ? B2 : B1;
    const int lda = seg ? lda2 : lda1;
    const int ldb = seg ? ldb2 : ldb1;
    const int K   = seg ? K2  : K1;
    for (int k0 = 0; k0 < K; k0 += 16) {
      float4 av = *(const float4*)(A + (size_t)(m0 + ldr) * lda + k0 + ldk);
      float4 bv = *(const float4*)(B + (size_t)(n0 + ldr) * ldb + k0 + ldk);
      __syncthreads();
      As[ldk + 0][ldr] = av.x; As[ldk + 1][ldr] = av.y;
      As[ldk + 2][ldr] = av.z; As[ldk + 3][ldr] = av.w;
      Bs[ldk + 0][ldr] = bv.x; Bs[ldk + 1][ldr] = bv.y;
      Bs[ldk + 2][ldr] = bv.z; Bs[ldk + 3][ldr] = bv.w;
      __syncthreads();
#pragma unroll
      for (int k = 0; k < 16; ++k) {
        float4 a = *(const float4*)&As[k][ty * 4];
        float4 b = *(const float4*)&Bs[k][tx * 4];
        acc[0][0] += a.x * b.x; acc[0][1] += a.x * b.y; acc[0][2] += a.x * b.z; acc[0][3] += a.x * b.w;
        acc[1][0] += a.y * b.x; acc[1][1] += a.y * b.y; acc[1][2] += a.y * b.z; acc[1][3] += a.y * b.w;
        acc[2][0] += a.z * b.x; acc[2][1] += a.z * b.y; acc[2][2] += a.z * b.z; acc[2][3] += a.z * b.w;
        acc[3][0] += a.w * b.x; acc[3][1] += a.w * b.y; acc[3][2] += a.w * b.z; acc[3][3] += a.w * b.w;
      }
    }
  }
  const float* bias = biasExt ? biasExt : (biasOff >= 0 ? g_ws + biasOff : nullptr);
  float* C = g_ws + offC;
#pragma unroll
  for (int i = 0; i < 4; ++i) {
    int row = m0 + ty * 4 + i;
    int col = n0 + tx * 4;
    float4 o;
    o.x = acc[i][0]; o.y = acc[i][1]; o.z = acc[i][2]; o.w = acc[i][3];
    if (bias) {
      o.x += bias[col]; o.y += bias[col + 1]; o.z += bias[col + 2]; o.w += bias[col + 3];
    }
    *(float4*)(C + (size_t)row * ldc + col) = o;
  }
}

// ---------------- LSTM cell elementwise (layer 0); sums NPART gate partials ----
__global__ __launch_bounds__(256) void lstm_cell(long hoff, long coff)
{
  int idx = blockIdx.x * 256 + threadIdx.x;   // 0..262143
  int r = idx >> 9, j = idx & 511;
  float gi = 0.f, gf = 0.f, gg = 0.f, go = 0.f;
  const size_t rb = (size_t)r * NGATE;
#pragma unroll
  for (int p = 0; p < NPART; ++p) {
    const float* gr = g_ws + OFF_G + (size_t)p * GPSTRIDE + rb;
    gi += gr[j]; gf += gr[512 + j]; gg += gr[1024 + j]; go += gr[1536 + j];
  }
  float* h = g_ws + hoff;
  float* c = g_ws + coff;
  float cold = c[(size_t)r * 1024 + j];
  float cn = sigf(gf) * cold + sigf(gi) * tanhf(gg);
  float hn = sigf(go) * tanhf(cn);
  c[(size_t)r * 1024 + j] = cn;
  h[(size_t)r * 1024 + j] = hn;
}

// ---------------- attn_mega: cell1 + q + attention + cproj, 4 rows/block -------
// Bit-exact replication of the baseline's split-K chunk arithmetic.
__global__ __launch_bounds__(512) void attn_mega(
    const float* __restrict__ kv, const void* __restrict__ kvm_raw,
    const float* __restrict__ W_attn, const float* __restrict__ W_cproj,
    const float* __restrict__ b_cproj)
{
  __shared__ float h1s[4][512];
  __shared__ float qs[4][512];
  __shared__ float scb[4][256];
  __shared__ float ctxs[4][512];
  const int b = blockIdx.x;            // 0..127
  const int tid = threadIdx.x;         // 0..511
  const int lane = tid & 63, wv = tid >> 6;

  // ---- phase A: LSTM cell layer 1 for rows 4b..4b+3 (exact lstm_cell body) ----
  for (int e = tid; e < 2048; e += 512) {
    const int s = e >> 9, j = e & 511;
    const int row = b * 4 + s;
    float gi = 0.f, gf = 0.f, gg = 0.f, go = 0.f;
    const size_t rb = (size_t)row * NGATE;
#pragma unroll
    for (int p = 0; p < NPART; ++p) {
      const float* gr = g_ws + OFF_G + (size_t)p * GPSTRIDE + rb;
      gi += gr[j]; gf += gr[512 + j]; gg += gr[1024 + j]; go += gr[1536 + j];
    }
    float* h = g_ws + OFF_H + 512;
    float* c = g_ws + OFF_C + 512;
    float cold = c[(size_t)row * 1024 + j];
    float cn = sigf(gf) * cold + sigf(gi) * tanhf(gg);
    float hn = sigf(go) * tanhf(cn);
    c[(size_t)row * 1024 + j] = cn;
    h[(size_t)row * 1024 + j] = hn;
    h1s[s][j] = hn;
  }
  __syncthreads();

  // ---- phase B: q[s][d] = h1 @ W_attn^T, 8 chunks of 64 (split-K replication) --
  {
    const int d = tid;
    const float* wr = W_attn + (size_t)d * 512;
    float t0 = 0.f, t1 = 0.f, t2 = 0.f, t3 = 0.f;
#pragma unroll 1
    for (int p = 0; p < 8; ++p) {
      float a0 = 0.f, a1 = 0.f, a2 = 0.f, a3 = 0.f;
      const int k0 = p * 64;
      for (int k = 0; k < 64; ++k) {
        const float w = wr[k0 + k];
        a0 += h1s[0][k0 + k] * w; a1 += h1s[1][k0 + k] * w;
        a2 += h1s[2][k0 + k] * w; a3 += h1s[3][k0 + k] * w;
      }
      t0 += a0; t1 += a1; t2 += a2; t3 += a3;
    }
    qs[0][d] = t0; qs[1][d] = t1; qs[2][d] = t2; qs[3][d] = t3;
  }
  __syncthreads();

  // ---- phase C: scores (exact baseline per-score math; 8 waves, m += 8) ----
  {
    const float* kvb = kv + (size_t)b * MLEN * HID;
    const unsigned* w32 = (const unsigned*)kvm_raw;
    const unsigned char* u8 = (const unsigned char*)kvm_raw;
    const bool u8mode = (w32[0] == 0x01010101u);
    for (int m = wv; m < MLEN; m += 8) {
      const float* kr = kvb + (size_t)m * HID;
      float a0 = 0.f, a1 = 0.f, a2 = 0.f, a3 = 0.f;
      for (int d = lane; d < HID; d += 64) {
        float kvv = kr[d];
        a0 += qs[0][d] * kvv; a1 += qs[1][d] * kvv;
        a2 += qs[2][d] * kvv; a3 += qs[3][d] * kvv;
      }
#pragma unroll
      for (int off = 32; off > 0; off >>= 1) {
        a0 += __shfl_down(a0, off); a1 += __shfl_down(a1, off);
        a2 += __shfl_down(a2, off); a3 += __shfl_down(a3, off);
      }
      if (lane == 0) {
        bool on = u8mode ? (u8[b * MLEN + m] != 0) : (w32[b * MLEN + m] != 0u);
        float madd = on ? 0.0f : -1e9f;
        scb[0][m] = a0 + madd; scb[1][m] = a1 + madd;
        scb[2][m] = a2 + madd; scb[3][m] = a3 + madd;
      }
    }
  }
  __syncthreads();

  // ---- phase D: softmax, wave s handles sample s (exact baseline) ----
  if (wv < 4) {
    const int s = wv;
    float mx = -3.4e38f;
    for (int m = lane; m < MLEN; m += 64) mx = fmaxf(mx, scb[s][m]);
#pragma unroll
    for (int off = 32; off > 0; off >>= 1) mx = fmaxf(mx, __shfl_xor(mx, off));
    float sum = 0.f;
    for (int m = lane; m < MLEN; m += 64) {
      float e = expf(scb[s][m] - mx);
      scb[s][m] = e; sum += e;
    }
#pragma unroll
    for (int off = 32; off > 0; off >>= 1) sum += __shfl_xor(sum, off);
    for (int m = lane; m < MLEN; m += 64) scb[s][m] = scb[s][m] / sum;
  }
  __syncthreads();

  // ---- phase E: ctx[s][col], m ascending (exact per-element order) ----
  {
    const float* kvb = kv + (size_t)b * MLEN * HID;
    float c0 = 0.f, c1 = 0.f, c2 = 0.f, c3 = 0.f;
    for (int m = 0; m < MLEN; ++m) {
      float kvv = kvb[(size_t)m * HID + tid];
      c0 += scb[0][m] * kvv; c1 += scb[1][m] * kvv;
      c2 += scb[2][m] * kvv; c3 += scb[3][m] * kvv;
    }
    ctxs[0][tid] = c0; ctxs[1][tid] = c1; ctxs[2][tid] = c2; ctxs[3][tid] = c3;
  }
  __syncthreads();

  // ---- phase F: out2[row][n] = [h1|ctx] @ W_cproj^T + b (split-K replication) --
  {
    const int n = tid;
    const float* wr = W_cproj + (size_t)n * 1024;
    const float bn = b_cproj[n];
    float t0 = 0.f, t1 = 0.f, t2 = 0.f, t3 = 0.f;
#pragma unroll 1
    for (int p = 0; p < 8; ++p) {
      float a0 = 0.f, a1 = 0.f, a2 = 0.f, a3 = 0.f;
      const int kb = p * 128;
      if (p < 4) {
        for (int k = 0; k < 128; ++k) {
          const float w = wr[kb + k];
          a0 += h1s[0][kb + k] * w; a1 += h1s[1][kb + k] * w;
          a2 += h1s[2][kb + k] * w; a3 += h1s[3][kb + k] * w;
        }
      } else {
        const int cb = kb - 512;
        for (int k = 0; k < 128; ++k) {
          const float w = wr[kb + k];
          a0 += ctxs[0][cb + k] * w; a1 += ctxs[1][cb + k] * w;
          a2 += ctxs[2][cb + k] * w; a3 += ctxs[3][cb + k] * w;
        }
      }
      if (p == 0) {   // partial 0 carried the bias in the baseline
        t0 = a0 + bn; t1 = a1 + bn; t2 = a2 + bn; t3 = a3 + bn;
      } else {
        t0 += a0; t1 += a1; t2 += a2; t3 += a3;
      }
    }
    float* o2 = g_ws + OFF_O2;
    o2[(size_t)(b * 4 + 0) * 512 + n] = t0;
    o2[(size_t)(b * 4 + 1) * 512 + n] = t1;
    o2[(size_t)(b * 4 + 2) * 512 + n] = t2;
    o2[(size_t)(b * 4 + 3) * 512 + n] = t3;
  }
}

// ---------------- sample_mega: logits + categorical sampling, 4 rows/block -----
__global__ __launch_bounds__(512) void sample_mega(
    const float* __restrict__ emb, const float* __restrict__ W_out,
    const float* __restrict__ b_out, int t)
{
  __shared__ float o2s[4][512];
  __shared__ float lgs[4][512];
  const int b = blockIdx.x;            // 0..127
  const int tid = threadIdx.x;
  const int lane = tid & 63, wv = tid >> 6;

  for (int e = tid; e < 2048; e += 512) {
    const int s = e >> 9, j = e & 511;
    o2s[s][j] = g_ws[OFF_O2 + (size_t)(b * 4 + s) * 512 + j];
  }
  __syncthreads();

  // logits[s][v], 8 chunks of 64, bias on chunk 0 (split-K replication)
  {
    const int v = tid;
    const float* wr = W_out + (size_t)v * 512;
    const float bv = b_out[v];
    float t0 = 0.f, t1 = 0.f, t2 = 0.f, t3 = 0.f;
#pragma unroll 1
    for (int p = 0; p < 8; ++p) {
      float a0 = 0.f, a1 = 0.f, a2 = 0.f, a3 = 0.f;
      const int k0 = p * 64;
      for (int k = 0; k < 64; ++k) {
        const float w = wr[k0 + k];
        a0 += o2s[0][k0 + k] * w; a1 += o2s[1][k0 + k] * w;
        a2 += o2s[2][k0 + k] * w; a3 += o2s[3][k0 + k] * w;
      }
      if (p == 0) { t0 = a0 + bv; t1 = a1 + bv; t2 = a2 + bv; t3 = a3 + bv; }
      else        { t0 += a0; t1 += a1; t2 += a2; t3 += a3; }
    }
    lgs[0][v] = t0; lgs[1][v] = t1; lgs[2][v] = t2; lgs[3][v] = t3;
  }
  __syncthreads();

  // sampling: wave wv (0..3) handles row 4b+wv; waves 4..7 done
  if (wv < 4) {
    const int row = b * 4 + wv;
    unsigned fk0 = 0u, fk1 = (unsigned)t;
    threefry2x32(0u, 42u, fk0, fk1);

    // ---- max of logits (order-free, exact) ----
    float m = -3.4e38f;
#pragma unroll
    for (int j = 0; j < 8; ++j) m = fmaxf(m, lgs[wv][lane + j * 64]);
#pragma unroll
    for (int off = 32; off > 0; off >>= 1) m = fmaxf(m, __shfl_xor(m, off));

    // ---- argmax of l+gumbel with (max, min-index) rule (order-free, exact) ----
    float bz = -3.4e38f; int bi = VOC;
#pragma unroll
    for (int j = 0; j < 8; ++j) {
      const int v = lane + j * 64;
      unsigned c0 = 0u, c1 = (unsigned)(row * VOC + v);
      threefry2x32(fk0, fk1, c0, c1);
      float z = lgs[wv][v] + gumbel_from_bits(c0 ^ c1);
      if (z > bz || (z == bz && v < bi)) { bz = z; bi = v; }
    }
#pragma unroll
    for (int off = 32; off > 0; off >>= 1) {
      float oz = __shfl_xor(bz, off); int oi = __shfl_xor(bi, off);
      if (oz > bz || (oz == bz && oi < bi)) { bz = oz; bi = oi; }
    }
    const int idx = bi;                 // same in all lanes

    // ---- S and W sums replicating the baseline's 256-entry LDS tree exactly.
    // Baseline lane value after the s=128 and s=64 steps:
    //   T(l) = ((E(l)+E(l+256)) + (E(l+128)+E(l+384)))
    //        + ((E(l+64)+E(l+320)) + (E(l+192)+E(l+448)))
    // then fan-in 32,16,8,4,2,1 — reproduced with shfl_down.
    float e0  = expf(lgs[wv][lane      ] - m), e1 = expf(lgs[wv][lane + 256] - m);
    float e2  = expf(lgs[wv][lane + 128] - m), e3 = expf(lgs[wv][lane + 384] - m);
    float e4  = expf(lgs[wv][lane +  64] - m), e5 = expf(lgs[wv][lane + 320] - m);
    float e6  = expf(lgs[wv][lane + 192] - m), e7 = expf(lgs[wv][lane + 448] - m);
    float d0  = lgs[wv][lane      ] - m, d1 = lgs[wv][lane + 256] - m;
    float d2  = lgs[wv][lane + 128] - m, d3 = lgs[wv][lane + 384] - m;
    float d4  = lgs[wv][lane +  64] - m, d5 = lgs[wv][lane + 320] - m;
    float d6  = lgs[wv][lane + 192] - m, d7 = lgs[wv][lane + 448] - m;
    float S = ((e0 + e1) + (e2 + e3)) + ((e4 + e5) + (e6 + e7));
    float W = ((e0 * d0 + e1 * d1) + (e2 * d2 + e3 * d3))
            + ((e4 * d4 + e5 * d5) + (e6 * d6 + e7 * d7));
#pragma unroll
    for (int off = 32; off > 0; off >>= 1) {
      S += __shfl_down(S, off);
      W += __shfl_down(W, off);
    }

    if (lane == 0) {
      const float l_at = lgs[wv][idx];
      const float logS = logf(S);
      g_ids[t * BN + row] = idx;
      g_ws[OFF_SLP + t * BN + row] = (l_at - m) - logS;
      atomicAdd(&g_ws[OFF_ENT + t], logS - W / S);
    }

    // next-step embedding
    float* xbuf = g_ws + OFF_X;
    const float* er = emb + (size_t)idx * EMBD;
    *(float4*)&xbuf[(size_t)row * EMBD + lane * 8]     = *(const float4*)&er[lane * 8];
    *(float4*)&xbuf[(size_t)row * EMBD + lane * 8 + 4] = *(const float4*)&er[lane * 8 + 4];
  }
}

// ---------------- init ----------------
__global__ __launch_bounds__(256) void init_misc(
    const float* __restrict__ y, const float* __restrict__ emb,
    const float* __restrict__ b_ih, const float* __restrict__ b_hh)
{
  int gid = blockIdx.x * 256 + threadIdx.x;
  int r = gid >> 9, col = gid & 511;
  g_ws[OFF_YR + gid] = y[(size_t)(r >> 2) * HID + col];
  g_ws[OFF_X + gid]  = emb[(size_t)(VOC - 1) * EMBD + col];
  if (gid < 2 * NGATE) g_ws[OFF_BG + gid] = b_ih[gid] + b_hh[gid];
  if (gid < 128) g_ws[OFF_ENT + gid] = 0.0f;
}

// ---------------- SINGLE output writer (f32) ----------------
__global__ __launch_bounds__(256) void write_out(
    const float* __restrict__ emb, const float* __restrict__ zmask,
    float* __restrict__ out)
{
  long i = (long)blockIdx.x * 256 + threadIdx.x;
  const long stride = (long)gridDim.x * 256;
  for (; i < O_TOTAL; i += stride) {
    float v;
    if (i < O_ZSTATES) {
      int bs = (int)(i / TLEN), t = (int)(i % TLEN);
      v = (float)g_ids[t * BN + bs];
    } else if (i < O_ZLP) {
      long j = i - O_ZSTATES;
      int e = (int)(j & 511);
      int bst = (int)(j >> 9);
      int bs = bst / TLEN, t = bst % TLEN;
      v = emb[(size_t)g_ids[t * BN + bs] * EMBD + e];
    } else if (i < O_STEP) {
      int bs = (int)(i - O_ZLP);
      int b = bs >> 2;
      float acc = 0.f;
      for (int t = 0; t < TLEN; ++t)
        acc += g_ws[OFF_SLP + t * BN + bs] * zmask[b * TLEN + t];
      v = acc;
    } else if (i < O_ENT) {
      long j = i - O_STEP;
      int bs = (int)(j / TLEN), t = (int)(j % TLEN);
      v = g_ws[OFF_SLP + t * BN + bs];
    } else {
      float e = 0.f;
      for (int t = 0; t < TLEN; ++t) e += g_ws[OFF_ENT + t];
      v = e / (float)(BN * TLEN);
    }
    out[i] = v;
  }
}

// ---------------- host ----------------
extern "C" void kernel_launch(void* const* d_in, const int* in_sizes, int n_in,
                              void* d_out, int out_size, void* d_ws, size_t ws_size,
                              hipStream_t stream) {
  (void)in_sizes; (void)n_in; (void)out_size; (void)d_ws; (void)ws_size;
  const float* y       = (const float*)d_in[0];
  const float* kv      = (const float*)d_in[1];
  const void*  kvm     = (const void*)d_in[2];
  const float* zmask   = (const float*)d_in[3];
  const float* emb     = (const float*)d_in[4];
  const float* W_h0    = (const float*)d_in[5];
  const float* b_h0    = (const float*)d_in[6];
  const float* W_c0    = (const float*)d_in[7];
  const float* b_c0    = (const float*)d_in[8];
  const float* W_ih    = (const float*)d_in[9];
  const float* W_hh    = (const float*)d_in[10];
  const float* b_ih    = (const float*)d_in[11];
  const float* b_hh    = (const float*)d_in[12];
  const float* W_attn  = (const float*)d_in[13];
  const float* W_cproj = (const float*)d_in[14];
  const float* b_cproj = (const float*)d_in[15];
  const float* W_out   = (const float*)d_in[16];
  const float* b_out   = (const float*)d_in[17];
  float* out = (float*)d_out;

  init_misc<<<1024, 256, 0, stream>>>(y, emb, b_ih, b_hh);

  // init h0 / c0 (outside loop)
  dim3 g_init(1024 / 64, 512 / 64);
  gemm2<<<g_init, 256, 0, stream>>>(OFF_YR, 512, W_h0, 512, 512,
                                    0L, 0, nullptr, 0, 0, b_h0, -1L, OFF_H, 1024);
  gemm2<<<g_init, 256, 0, stream>>>(OFF_YR, 512, W_c0, 512, 512,
                                    0L, 0, nullptr, 0, 0, b_c0, -1L, OFF_C, 1024);

  dim3 g_gates(2048 / 64, 512 / 64, NPART);   // Kc=128 over K=1024
  const size_t WL = (size_t)NGATE * HID;

  for (int t = 0; t < TLEN; ++t) {
    // layer 0 gates
    gemmsk<<<g_gates, 64, 0, stream>>>(OFF_X, 512, 1, 0L, W_ih, 512, 512,
                                       OFF_H, 1024, W_hh, 512,
                                       nullptr, OFF_BG, OFF_G, NGATE, 128);
    lstm_cell<<<1024, 256, 0, stream>>>(OFF_H, OFF_C);
    // layer 1 gates
    gemmsk<<<g_gates, 64, 0, stream>>>(OFF_H, 1024, 1, 0L, W_ih + WL, 512, 512,
                                       OFF_H + 512, 1024, W_hh + WL, 512,
                                       nullptr, OFF_BG + NGATE, OFF_G, NGATE, 128);
    // cell1 + q + attention + cproj
    attn_mega<<<128, 512, 0, stream>>>(kv, kvm, W_attn, W_cproj, b_cproj);
    // logits + sampling
    sample_mega<<<128, 512, 0, stream>>>(emb, W_out, b_out, t);
  }

  int wblocks = (int)((O_TOTAL + 255L) / 256L);
  write_out<<<wblocks, 256, 0, stream>>>(emb, zmask, out);
}

// Round 3
// 24293.704 us; speedup vs baseline: 3.3377x; 1.0450x over previous
//
#include <hip/hip_runtime.h>

// Problem constants (fixed by harness inputs)
#define BATCH 128
#define NSAMP 4
#define BN    512        // BATCH*NSAMP
#define HID   512
#define EMBD  512
#define VOC   512
#define TLEN  100
#define MLEN  256
#define NGATE 2048       // 4*HID

#define NPART 8          // split-K partials for gate GEMMs (bit-exact contract)

// output flat offsets (FLOAT32 elements)
#define O_ZID     0L
#define O_ZSTATES 51200L
#define O_ZLP     26265600L
#define O_STEP    26266112L
#define O_ENT     26317312L
#define O_TOTAL   26317313L

// workspace offsets (floats) inside g_ws
#define OFF_H    0L          // [512][1024]
#define OFF_C    524288L     // [512][1024]
#define OFF_X    1048576L    // [512][512]
#define OFF_G    1310720L    // 8 x [512][2048]
#define OFF_O2   12058624L   // [512][512] (single buffer)
#define OFF_YR   16252928L   // [512][512]
#define OFF_BG   16515072L   // [2][2048]
#define OFF_ENT  16519168L   // [128]
#define OFF_SLP  16519296L   // [100*512]
#define OFF_WAT  16570496L   // [512][512]  W_attn^T  (k-major)
#define OFF_WCT  16832640L   // [1024][512] W_cproj^T (k-major)
#define OFF_WOT  17356928L   // [512][512]  W_out^T   (k-major)
#define WS_FLOATS 17619072L

#define GPSTRIDE 1048576L    // 512*2048 gate-partial stride

__device__ float g_ws[WS_FLOATS];
__device__ int   g_ids[TLEN * BN];

// ---------------- threefry2x32 (JAX-exact, 20 rounds) ----------------
__device__ __forceinline__ unsigned rotl32(unsigned x, int r) {
  return (x << r) | (x >> (32 - r));
}
__device__ __forceinline__ void threefry2x32(unsigned k0, unsigned k1,
                                             unsigned& x0, unsigned& x1) {
  unsigned k2 = k0 ^ k1 ^ 0x1BD11BDAu;
#define TF_R(r) { x0 += x1; x1 = rotl32(x1, r); x1 ^= x0; }
  x0 += k0; x1 += k1;
  TF_R(13) TF_R(15) TF_R(26) TF_R(6)
  x0 += k1; x1 += k2 + 1u;
  TF_R(17) TF_R(29) TF_R(16) TF_R(24)
  x0 += k2; x1 += k0 + 2u;
  TF_R(13) TF_R(15) TF_R(26) TF_R(6)
  x0 += k0; x1 += k1 + 3u;
  TF_R(17) TF_R(29) TF_R(16) TF_R(24)
  x0 += k1; x1 += k2 + 4u;
  TF_R(13) TF_R(15) TF_R(26) TF_R(6)
  x0 += k2; x1 += k0 + 5u;
#undef TF_R
}

__device__ __forceinline__ float gumbel_from_bits(unsigned bits) {
  unsigned fb = (bits >> 9) | 0x3F800000u;
  float f = __uint_as_float(fb) - 1.0f;          // [0,1)
  const float TINY = 1.17549435e-38f;
  float u = fmaxf(f + TINY, TINY);
  return -logf(-logf(u));
}

// XLA-style logistic: 0.5 + 0.5*tanh(0.5*x)
__device__ __forceinline__ float sigf(float x) {
  return 0.5f + 0.5f * tanhf(0.5f * x);
}

__device__ __forceinline__ float4 add4(float4 a, float4 b) {
  a.x += b.x; a.y += b.y; a.z += b.z; a.w += b.w; return a;
}

// ---------------- split-K fp32 GEMM: 64 threads, 64x64 tile, 8x8 micro, BK=16 ----
// (verbatim baseline — gate GEMMs only)
__global__ __launch_bounds__(64) void gemmsk(
    long offA1, int lda1, int P1, long strideP1,
    const float* __restrict__ B1, int ldb1, int K1,
    long offA2, int lda2,
    const float* __restrict__ B2, int ldb2,
    const float* __restrict__ biasExt, long biasOff,
    long offC, int ldc, int Kc)
{
  __shared__ float As[16][64];
  __shared__ float Bs[16][64];
  const int t  = threadIdx.x;
  const int tm = t >> 3;         // 0..7
  const int tn = t & 7;          // 0..7
  const int m0 = blockIdx.y * 64;
  const int n0 = blockIdx.x * 64;
  const int kp = blockIdx.z;

  int kbase = kp * Kc;
  const float* A; const float* B; int lda, ldb, P; long strideP;
  if (kbase < K1) {
    A = g_ws + offA1; B = B1; lda = lda1; ldb = ldb1; P = P1; strideP = strideP1;
  } else {
    A = g_ws + offA2; B = B2; lda = lda2; ldb = ldb2; P = 1; strideP = 0;
    kbase -= K1;
  }

  float acc[8][8];
#pragma unroll
  for (int i = 0; i < 8; ++i)
#pragma unroll
    for (int j = 0; j < 8; ++j) acc[i][j] = 0.f;

  for (int k0 = 0; k0 < Kc; k0 += 16) {
    const int kg = kbase + k0;
    const float* pa = A + (size_t)(m0 + t) * lda + kg;
    float4 a0, a1, a2, a3;
    {
      const float4* q4 = (const float4*)pa;
      a0 = q4[0]; a1 = q4[1]; a2 = q4[2]; a3 = q4[3];
      for (int p = 1; p < P; ++p) {
        const float4* r4 = (const float4*)(pa + (size_t)p * strideP);
        a0 = add4(a0, r4[0]); a1 = add4(a1, r4[1]);
        a2 = add4(a2, r4[2]); a3 = add4(a3, r4[3]);
      }
    }
    const float4* pb = (const float4*)(B + (size_t)(n0 + t) * ldb + kg);
    float4 b0 = pb[0], b1 = pb[1], b2 = pb[2], b3 = pb[3];

    __syncthreads();
    As[ 0][t] = a0.x; As[ 1][t] = a0.y; As[ 2][t] = a0.z; As[ 3][t] = a0.w;
    As[ 4][t] = a1.x; As[ 5][t] = a1.y; As[ 6][t] = a1.z; As[ 7][t] = a1.w;
    As[ 8][t] = a2.x; As[ 9][t] = a2.y; As[10][t] = a2.z; As[11][t] = a2.w;
    As[12][t] = a3.x; As[13][t] = a3.y; As[14][t] = a3.z; As[15][t] = a3.w;
    Bs[ 0][t] = b0.x; Bs[ 1][t] = b0.y; Bs[ 2][t] = b0.z; Bs[ 3][t] = b0.w;
    Bs[ 4][t] = b1.x; Bs[ 5][t] = b1.y; Bs[ 6][t] = b1.z; Bs[ 7][t] = b1.w;
    Bs[ 8][t] = b2.x; Bs[ 9][t] = b2.y; Bs[10][t] = b2.z; Bs[11][t] = b2.w;
    Bs[12][t] = b3.x; Bs[13][t] = b3.y; Bs[14][t] = b3.z; Bs[15][t] = b3.w;
    __syncthreads();

#pragma unroll
    for (int k = 0; k < 16; ++k) {
      float av[8], bv[8];
      *(float4*)&av[0] = *(const float4*)&As[k][tm * 8];
      *(float4*)&av[4] = *(const float4*)&As[k][tm * 8 + 4];
      *(float4*)&bv[0] = *(const float4*)&Bs[k][tn * 8];
      *(float4*)&bv[4] = *(const float4*)&Bs[k][tn * 8 + 4];
#pragma unroll
      for (int i = 0; i < 8; ++i)
#pragma unroll
        for (int j = 0; j < 8; ++j)
          acc[i][j] += av[i] * bv[j];
    }
  }

  const int Mtot = gridDim.y * 64;
  float* C = g_ws + offC + (size_t)kp * (size_t)Mtot * ldc;
  const float* bias = nullptr;
  if (kp == 0)
    bias = biasExt ? biasExt : (biasOff >= 0 ? g_ws + biasOff : nullptr);
#pragma unroll
  for (int i = 0; i < 8; ++i) {
    const int row = m0 + tm * 8 + i;
    const int col = n0 + tn * 8;
    float4 o0, o1;
    o0.x = acc[i][0]; o0.y = acc[i][1]; o0.z = acc[i][2]; o0.w = acc[i][3];
    o1.x = acc[i][4]; o1.y = acc[i][5]; o1.z = acc[i][6]; o1.w = acc[i][7];
    if (bias) {
      o0.x += bias[col];     o0.y += bias[col + 1];
      o0.z += bias[col + 2]; o0.w += bias[col + 3];
      o1.x += bias[col + 4]; o1.y += bias[col + 5];
      o1.z += bias[col + 6]; o1.w += bias[col + 7];
    }
    *(float4*)(C + (size_t)row * ldc + col)     = o0;
    *(float4*)(C + (size_t)row * ldc + col + 4) = o1;
  }
}

// ---------------- old single-pass GEMM (init h0/c0 only) ----------------
__global__ __launch_bounds__(256) void gemm2(
    long offA1, int lda1,
    const float* __restrict__ B1, int ldb1, int K1,
    long offA2, int lda2,
    const float* __restrict__ B2, int ldb2, int K2,
    const float* __restrict__ biasExt, long biasOff,
    long offC, int ldc)
{
  __shared__ float As[16][68];
  __shared__ float Bs[16][68];
  const int tid = threadIdx.x;
  const int tx  = tid & 15;
  const int ty  = tid >> 4;
  const int ldr = tid >> 2;
  const int ldk = (tid & 3) << 2;
  const int m0 = blockIdx.y * 64;
  const int n0 = blockIdx.x * 64;
  float acc[4][4] = {{0.f}};

  for (int seg = 0; seg < 2; ++seg) {
    const float* A = g_ws + (seg ? offA2 : offA1);
    const float* B = seg ? B2 : B1;
    const int lda = seg ? lda2 : lda1;
    const int ldb = seg ? ldb2 : ldb1;
    const int K   = seg ? K2  : K1;
    for (int k0 = 0; k0 < K; k0 += 16) {
      float4 av = *(const float4*)(A + (size_t)(m0 + ldr) * lda + k0 + ldk);
      float4 bv = *(const float4*)(B + (size_t)(n0 + ldr) * ldb + k0 + ldk);
      __syncthreads();
      As[ldk + 0][ldr] = av.x; As[ldk + 1][ldr] = av.y;
      As[ldk + 2][ldr] = av.z; As[ldk + 3][ldr] = av.w;
      Bs[ldk + 0][ldr] = bv.x; Bs[ldk + 1][ldr] = bv.y;
      Bs[ldk + 2][ldr] = bv.z; Bs[ldk + 3][ldr] = bv.w;
      __syncthreads();
#pragma unroll
      for (int k = 0; k < 16; ++k) {
        float4 a = *(const float4*)&As[k][ty * 4];
        float4 b = *(const float4*)&Bs[k][tx * 4];
        acc[0][0] += a.x * b.x; acc[0][1] += a.x * b.y; acc[0][2] += a.x * b.z; acc[0][3] += a.x * b.w;
        acc[1][0] += a.y * b.x; acc[1][1] += a.y * b.y; acc[1][2] += a.y * b.z; acc[1][3] += a.y * b.w;
        acc[2][0] += a.z * b.x; acc[2][1] += a.z * b.y; acc[2][2] += a.z * b.z; acc[2][3] += a.z * b.w;
        acc[3][0] += a.w * b.x; acc[3][1] += a.w * b.y; acc[3][2] += a.w * b.z; acc[3][3] += a.w * b.w;
      }
    }
  }
  const float* bias = biasExt ? biasExt : (biasOff >= 0 ? g_ws + biasOff : nullptr);
  float* C = g_ws + offC;
#pragma unroll
  for (int i = 0; i < 4; ++i) {
    int row = m0 + ty * 4 + i;
    int col = n0 + tx * 4;
    float4 o;
    o.x = acc[i][0]; o.y = acc[i][1]; o.z = acc[i][2]; o.w = acc[i][3];
    if (bias) {
      o.x += bias[col]; o.y += bias[col + 1]; o.z += bias[col + 2]; o.w += bias[col + 3];
    }
    *(float4*)(C + (size_t)row * ldc + col) = o;
  }
}

// ---------------- LSTM cell elementwise (layer 0); sums NPART gate partials ----
__global__ __launch_bounds__(256) void lstm_cell(long hoff, long coff)
{
  int idx = blockIdx.x * 256 + threadIdx.x;   // 0..262143
  int r = idx >> 9, j = idx & 511;
  float gi = 0.f, gf = 0.f, gg = 0.f, go = 0.f;
  const size_t rb = (size_t)r * NGATE;
#pragma unroll
  for (int p = 0; p < NPART; ++p) {
    const float* gr = g_ws + OFF_G + (size_t)p * GPSTRIDE + rb;
    gi += gr[j]; gf += gr[512 + j]; gg += gr[1024 + j]; go += gr[1536 + j];
  }
  float* h = g_ws + hoff;
  float* c = g_ws + coff;
  float cold = c[(size_t)r * 1024 + j];
  float cn = sigf(gf) * cold + sigf(gi) * tanhf(gg);
  float hn = sigf(go) * tanhf(cn);
  c[(size_t)r * 1024 + j] = cn;
  h[(size_t)r * 1024 + j] = hn;
}

// ---------------- one-time weight transposes (k-major for coalesced reads) -----
__global__ __launch_bounds__(256) void transpose_w(
    const float* __restrict__ W_attn, const float* __restrict__ W_cproj,
    const float* __restrict__ W_out)
{
  int i = blockIdx.x * 256 + threadIdx.x;     // grid covers 1048576
  if (i < 262144) {
    int k = i >> 9, n = i & 511;
    g_ws[OFF_WAT + i] = W_attn[(size_t)n * 512 + k];
  } else if (i < 786432) {
    int j = i - 262144;
    int k = j >> 9, n = j & 511;
    g_ws[OFF_WCT + j] = W_cproj[(size_t)n * 1024 + k];
  } else if (i < 1048576) {
    int j = i - 786432;
    int k = j >> 9, n = j & 511;
    g_ws[OFF_WOT + j] = W_out[(size_t)n * 512 + k];
  }
}

// ---------------- attn_mega: cell1 + q + attention + cproj, 4 rows/block -------
// Bit-exact replication of the baseline split-K chunk arithmetic; weights read
// via the k-major transposed copies (same values, same order, coalesced).
__global__ __launch_bounds__(512) void attn_mega(
    const float* __restrict__ kv, const void* __restrict__ kvm_raw,
    const float* __restrict__ b_cproj)
{
  __shared__ float h1s[4][512];
  __shared__ float qs[4][512];
  __shared__ float scb[4][256];
  __shared__ float ctxs[4][512];
  const int b = blockIdx.x;            // 0..127
  const int tid = threadIdx.x;         // 0..511
  const int lane = tid & 63, wv = tid >> 6;

  // ---- phase A: LSTM cell layer 1 for rows 4b..4b+3 (exact lstm_cell body) ----
  for (int e = tid; e < 2048; e += 512) {
    const int s = e >> 9, j = e & 511;
    const int row = b * 4 + s;
    float gi = 0.f, gf = 0.f, gg = 0.f, go = 0.f;
    const size_t rb = (size_t)row * NGATE;
#pragma unroll
    for (int p = 0; p < NPART; ++p) {
      const float* gr = g_ws + OFF_G + (size_t)p * GPSTRIDE + rb;
      gi += gr[j]; gf += gr[512 + j]; gg += gr[1024 + j]; go += gr[1536 + j];
    }
    float* h = g_ws + OFF_H + 512;
    float* c = g_ws + OFF_C + 512;
    float cold = c[(size_t)row * 1024 + j];
    float cn = sigf(gf) * cold + sigf(gi) * tanhf(gg);
    float hn = sigf(go) * tanhf(cn);
    c[(size_t)row * 1024 + j] = cn;
    h[(size_t)row * 1024 + j] = hn;
    h1s[s][j] = hn;
  }
  __syncthreads();

  // ---- phase B: q[s][d] = h1 @ W_attn^T, 8 chunks of 64 (split-K replication) --
  {
    const int d = tid;
    const float* wt = g_ws + OFF_WAT;           // [k][n] k-major
    float t0 = 0.f, t1 = 0.f, t2 = 0.f, t3 = 0.f;
#pragma unroll 1
    for (int p = 0; p < 8; ++p) {
      float a0 = 0.f, a1 = 0.f, a2 = 0.f, a3 = 0.f;
      const int k0 = p * 64;
#pragma unroll
      for (int k = 0; k < 64; ++k) {
        const float w = wt[(size_t)(k0 + k) * 512 + d];
        a0 += h1s[0][k0 + k] * w; a1 += h1s[1][k0 + k] * w;
        a2 += h1s[2][k0 + k] * w; a3 += h1s[3][k0 + k] * w;
      }
      t0 += a0; t1 += a1; t2 += a2; t3 += a3;
    }
    qs[0][d] = t0; qs[1][d] = t1; qs[2][d] = t2; qs[3][d] = t3;
  }
  __syncthreads();

  // ---- phase C: scores (exact baseline per-score math; 8 waves, m += 8) ----
  {
    const float* kvb = kv + (size_t)b * MLEN * HID;
    const unsigned* w32 = (const unsigned*)kvm_raw;
    const unsigned char* u8 = (const unsigned char*)kvm_raw;
    const bool u8mode = (w32[0] == 0x01010101u);
    for (int m = wv; m < MLEN; m += 8) {
      const float* kr = kvb + (size_t)m * HID;
      float a0 = 0.f, a1 = 0.f, a2 = 0.f, a3 = 0.f;
      for (int d = lane; d < HID; d += 64) {
        float kvv = kr[d];
        a0 += qs[0][d] * kvv; a1 += qs[1][d] * kvv;
        a2 += qs[2][d] * kvv; a3 += qs[3][d] * kvv;
      }
#pragma unroll
      for (int off = 32; off > 0; off >>= 1) {
        a0 += __shfl_down(a0, off); a1 += __shfl_down(a1, off);
        a2 += __shfl_down(a2, off); a3 += __shfl_down(a3, off);
      }
      if (lane == 0) {
        bool on = u8mode ? (u8[b * MLEN + m] != 0) : (w32[b * MLEN + m] != 0u);
        float madd = on ? 0.0f : -1e9f;
        scb[0][m] = a0 + madd; scb[1][m] = a1 + madd;
        scb[2][m] = a2 + madd; scb[3][m] = a3 + madd;
      }
    }
  }
  __syncthreads();

  // ---- phase D: softmax, wave s handles sample s (exact baseline) ----
  if (wv < 4) {
    const int s = wv;
    float mx = -3.4e38f;
    for (int m = lane; m < MLEN; m += 64) mx = fmaxf(mx, scb[s][m]);
#pragma unroll
    for (int off = 32; off > 0; off >>= 1) mx = fmaxf(mx, __shfl_xor(mx, off));
    float sum = 0.f;
    for (int m = lane; m < MLEN; m += 64) {
      float e = expf(scb[s][m] - mx);
      scb[s][m] = e; sum += e;
    }
#pragma unroll
    for (int off = 32; off > 0; off >>= 1) sum += __shfl_xor(sum, off);
    for (int m = lane; m < MLEN; m += 64) scb[s][m] = scb[s][m] / sum;
  }
  __syncthreads();

  // ---- phase E: ctx[s][col], m ascending (exact per-element order) ----
  {
    const float* kvb = kv + (size_t)b * MLEN * HID;
    float c0 = 0.f, c1 = 0.f, c2 = 0.f, c3 = 0.f;
    for (int m = 0; m < MLEN; ++m) {
      float kvv = kvb[(size_t)m * HID + tid];
      c0 += scb[0][m] * kvv; c1 += scb[1][m] * kvv;
      c2 += scb[2][m] * kvv; c3 += scb[3][m] * kvv;
    }
    ctxs[0][tid] = c0; ctxs[1][tid] = c1; ctxs[2][tid] = c2; ctxs[3][tid] = c3;
  }
  __syncthreads();

  // ---- phase F: out2[row][n] = [h1|ctx] @ W_cproj^T + b (split-K replication) --
  {
    const int n = tid;
    const float* wt = g_ws + OFF_WCT;           // [k][n] k-major, k<1024
    const float bn = b_cproj[n];
    float t0 = 0.f, t1 = 0.f, t2 = 0.f, t3 = 0.f;
#pragma unroll 1
    for (int p = 0; p < 8; ++p) {
      float a0 = 0.f, a1 = 0.f, a2 = 0.f, a3 = 0.f;
      const int kb = p * 128;
      if (p < 4) {
#pragma unroll
        for (int k = 0; k < 128; ++k) {
          const float w = wt[(size_t)(kb + k) * 512 + n];
          a0 += h1s[0][kb + k] * w; a1 += h1s[1][kb + k] * w;
          a2 += h1s[2][kb + k] * w; a3 += h1s[3][kb + k] * w;
        }
      } else {
        const int cb = kb - 512;
#pragma unroll
        for (int k = 0; k < 128; ++k) {
          const float w = wt[(size_t)(kb + k) * 512 + n];
          a0 += ctxs[0][cb + k] * w; a1 += ctxs[1][cb + k] * w;
          a2 += ctxs[2][cb + k] * w; a3 += ctxs[3][cb + k] * w;
        }
      }
      if (p == 0) {   // partial 0 carried the bias in the baseline
        t0 = a0 + bn; t1 = a1 + bn; t2 = a2 + bn; t3 = a3 + bn;
      } else {
        t0 += a0; t1 += a1; t2 += a2; t3 += a3;
      }
    }
    float* o2 = g_ws + OFF_O2;
    o2[(size_t)(b * 4 + 0) * 512 + n] = t0;
    o2[(size_t)(b * 4 + 1) * 512 + n] = t1;
    o2[(size_t)(b * 4 + 2) * 512 + n] = t2;
    o2[(size_t)(b * 4 + 3) * 512 + n] = t3;
  }
}

// ---------------- sample_mega: logits + categorical sampling, 4 rows/block -----
__global__ __launch_bounds__(512) void sample_mega(
    const float* __restrict__ emb, const float* __restrict__ b_out, int t)
{
  __shared__ float o2s[4][512];
  __shared__ float lgs[4][512];
  const int b = blockIdx.x;            // 0..127
  const int tid = threadIdx.x;
  const int lane = tid & 63, wv = tid >> 6;

  for (int e = tid; e < 2048; e += 512) {
    const int s = e >> 9, j = e & 511;
    o2s[s][j] = g_ws[OFF_O2 + (size_t)(b * 4 + s) * 512 + j];
  }
  __syncthreads();

  // logits[s][v], 8 chunks of 64, bias on chunk 0 (split-K replication)
  {
    const int v = tid;
    const float* wt = g_ws + OFF_WOT;           // [k][v] k-major
    const float bv = b_out[v];
    float t0 = 0.f, t1 = 0.f, t2 = 0.f, t3 = 0.f;
#pragma unroll 1
    for (int p = 0; p < 8; ++p) {
      float a0 = 0.f, a1 = 0.f, a2 = 0.f, a3 = 0.f;
      const int k0 = p * 64;
#pragma unroll
      for (int k = 0; k < 64; ++k) {
        const float w = wt[(size_t)(k0 + k) * 512 + v];
        a0 += o2s[0][k0 + k] * w; a1 += o2s[1][k0 + k] * w;
        a2 += o2s[2][k0 + k] * w; a3 += o2s[3][k0 + k] * w;
      }
      if (p == 0) { t0 = a0 + bv; t1 = a1 + bv; t2 = a2 + bv; t3 = a3 + bv; }
      else        { t0 += a0; t1 += a1; t2 += a2; t3 += a3; }
    }
    lgs[0][v] = t0; lgs[1][v] = t1; lgs[2][v] = t2; lgs[3][v] = t3;
  }
  __syncthreads();

  // sampling: wave wv (0..3) handles row 4b+wv; waves 4..7 done
  if (wv < 4) {
    const int row = b * 4 + wv;
    unsigned fk0 = 0u, fk1 = (unsigned)t;
    threefry2x32(0u, 42u, fk0, fk1);

    // ---- max of logits (order-free, exact) ----
    float m = -3.4e38f;
#pragma unroll
    for (int j = 0; j < 8; ++j) m = fmaxf(m, lgs[wv][lane + j * 64]);
#pragma unroll
    for (int off = 32; off > 0; off >>= 1) m = fmaxf(m, __shfl_xor(m, off));

    // ---- argmax of l+gumbel with (max, min-index) rule (order-free, exact) ----
    float bz = -3.4e38f; int bi = VOC;
#pragma unroll
    for (int j = 0; j < 8; ++j) {
      const int v = lane + j * 64;
      unsigned c0 = 0u, c1 = (unsigned)(row * VOC + v);
      threefry2x32(fk0, fk1, c0, c1);
      float z = lgs[wv][v] + gumbel_from_bits(c0 ^ c1);
      if (z > bz || (z == bz && v < bi)) { bz = z; bi = v; }
    }
#pragma unroll
    for (int off = 32; off > 0; off >>= 1) {
      float oz = __shfl_xor(bz, off); int oi = __shfl_xor(bi, off);
      if (oz > bz || (oz == bz && oi < bi)) { bz = oz; bi = oi; }
    }
    const int idx = bi;                 // same in all lanes

    // ---- S and W sums replicating the baseline's 256-entry LDS tree exactly ----
    float e0  = expf(lgs[wv][lane      ] - m), e1 = expf(lgs[wv][lane + 256] - m);
    float e2  = expf(lgs[wv][lane + 128] - m), e3 = expf(lgs[wv][lane + 384] - m);
    float e4  = expf(lgs[wv][lane +  64] - m), e5 = expf(lgs[wv][lane + 320] - m);
    float e6  = expf(lgs[wv][lane + 192] - m), e7 = expf(lgs[wv][lane + 448] - m);
    float d0  = lgs[wv][lane      ] - m, d1 = lgs[wv][lane + 256] - m;
    float d2  = lgs[wv][lane + 128] - m, d3 = lgs[wv][lane + 384] - m;
    float d4  = lgs[wv][lane +  64] - m, d5 = lgs[wv][lane + 320] - m;
    float d6  = lgs[wv][lane + 192] - m, d7 = lgs[wv][lane + 448] - m;
    float S = ((e0 + e1) + (e2 + e3)) + ((e4 + e5) + (e6 + e7));
    float W = ((e0 * d0 + e1 * d1) + (e2 * d2 + e3 * d3))
            + ((e4 * d4 + e5 * d5) + (e6 * d6 + e7 * d7));
#pragma unroll
    for (int off = 32; off > 0; off >>= 1) {
      S += __shfl_down(S, off);
      W += __shfl_down(W, off);
    }

    if (lane == 0) {
      const float l_at = lgs[wv][idx];
      const float logS = logf(S);
      g_ids[t * BN + row] = idx;
      g_ws[OFF_SLP + t * BN + row] = (l_at - m) - logS;
      atomicAdd(&g_ws[OFF_ENT + t], logS - W / S);
    }

    // next-step embedding
    float* xbuf = g_ws + OFF_X;
    const float* er = emb + (size_t)idx * EMBD;
    *(float4*)&xbuf[(size_t)row * EMBD + lane * 8]     = *(const float4*)&er[lane * 8];
    *(float4*)&xbuf[(size_t)row * EMBD + lane * 8 + 4] = *(const float4*)&er[lane * 8 + 4];
  }
}

// ---------------- init ----------------
__global__ __launch_bounds__(256) void init_misc(
    const float* __restrict__ y, const float* __restrict__ emb,
    const float* __restrict__ b_ih, const float* __restrict__ b_hh)
{
  int gid = blockIdx.x * 256 + threadIdx.x;
  int r = gid >> 9, col = gid & 511;
  g_ws[OFF_YR + gid] = y[(size_t)(r >> 2) * HID + col];
  g_ws[OFF_X + gid]  = emb[(size_t)(VOC - 1) * EMBD + col];
  if (gid < 2 * NGATE) g_ws[OFF_BG + gid] = b_ih[gid] + b_hh[gid];
  if (gid < 128) g_ws[OFF_ENT + gid] = 0.0f;
}

// ---------------- SINGLE output writer (f32) ----------------
__global__ __launch_bounds__(256) void write_out(
    const float* __restrict__ emb, const float* __restrict__ zmask,
    float* __restrict__ out)
{
  long i = (long)blockIdx.x * 256 + threadIdx.x;
  const long stride = (long)gridDim.x * 256;
  for (; i < O_TOTAL; i += stride) {
    float v;
    if (i < O_ZSTATES) {
      int bs = (int)(i / TLEN), t = (int)(i % TLEN);
      v = (float)g_ids[t * BN + bs];
    } else if (i < O_ZLP) {
      long j = i - O_ZSTATES;
      int e = (int)(j & 511);
      int bst = (int)(j >> 9);
      int bs = bst / TLEN, t = bst % TLEN;
      v = emb[(size_t)g_ids[t * BN + bs] * EMBD + e];
    } else if (i < O_STEP) {
      int bs = (int)(i - O_ZLP);
      int b = bs >> 2;
      float acc = 0.f;
      for (int t = 0; t < TLEN; ++t)
        acc += g_ws[OFF_SLP + t * BN + bs] * zmask[b * TLEN + t];
      v = acc;
    } else if (i < O_ENT) {
      long j = i - O_STEP;
      int bs = (int)(j / TLEN), t = (int)(j % TLEN);
      v = g_ws[OFF_SLP + t * BN + bs];
    } else {
      float e = 0.f;
      for (int t = 0; t < TLEN; ++t) e += g_ws[OFF_ENT + t];
      v = e / (float)(BN * TLEN);
    }
    out[i] = v;
  }
}

// ---------------- host ----------------
extern "C" void kernel_launch(void* const* d_in, const int* in_sizes, int n_in,
                              void* d_out, int out_size, void* d_ws, size_t ws_size,
                              hipStream_t stream) {
  (void)in_sizes; (void)n_in; (void)out_size; (void)d_ws; (void)ws_size;
  const float* y       = (const float*)d_in[0];
  const float* kv      = (const float*)d_in[1];
  const void*  kvm     = (const void*)d_in[2];
  const float* zmask   = (const float*)d_in[3];
  const float* emb     = (const float*)d_in[4];
  const float* W_h0    = (const float*)d_in[5];
  const float* b_h0    = (const float*)d_in[6];
  const float* W_c0    = (const float*)d_in[7];
  const float* b_c0    = (const float*)d_in[8];
  const float* W_ih    = (const float*)d_in[9];
  const float* W_hh    = (const float*)d_in[10];
  const float* b_ih    = (const float*)d_in[11];
  const float* b_hh    = (const float*)d_in[12];
  const float* W_attn  = (const float*)d_in[13];
  const float* W_cproj = (const float*)d_in[14];
  const float* b_cproj = (const float*)d_in[15];
  const float* W_out   = (const float*)d_in[16];
  const float* b_out   = (const float*)d_in[17];
  float* out = (float*)d_out;

  init_misc<<<1024, 256, 0, stream>>>(y, emb, b_ih, b_hh);
  transpose_w<<<4096, 256, 0, stream>>>(W_attn, W_cproj, W_out);

  // init h0 / c0 (outside loop)
  dim3 g_init(1024 / 64, 512 / 64);
  gemm2<<<g_init, 256, 0, stream>>>(OFF_YR, 512, W_h0, 512, 512,
                                    0L, 0, nullptr, 0, 0, b_h0, -1L, OFF_H, 1024);
  gemm2<<<g_init, 256, 0, stream>>>(OFF_YR, 512, W_c0, 512, 512,
                                    0L, 0, nullptr, 0, 0, b_c0, -1L, OFF_C, 1024);

  dim3 g_gates(2048 / 64, 512 / 64, NPART);   // Kc=128 over K=1024
  const size_t WL = (size_t)NGATE * HID;

  for (int t = 0; t < TLEN; ++t) {
    // layer 0 gates
    gemmsk<<<g_gates, 64, 0, stream>>>(OFF_X, 512, 1, 0L, W_ih, 512, 512,
                                       OFF_H, 1024, W_hh, 512,
                                       nullptr, OFF_BG, OFF_G, NGATE, 128);
    lstm_cell<<<1024, 256, 0, stream>>>(OFF_H, OFF_C);
    // layer 1 gates
    gemmsk<<<g_gates, 64, 0, stream>>>(OFF_H, 1024, 1, 0L, W_ih + WL, 512, 512,
                                       OFF_H + 512, 1024, W_hh + WL, 512,
                                       nullptr, OFF_BG + NGATE, OFF_G, NGATE, 128);
    // cell1 + q + attention + cproj
    attn_mega<<<128, 512, 0, stream>>>(kv, kvm, b_cproj);
    // logits + sampling
    sample_mega<<<128, 512, 0, stream>>>(emb, b_out, t);
  }

  int wblocks = (int)((O_TOTAL + 255L) / 256L);
  write_out<<<wblocks, 256, 0, stream>>>(emb, zmask, out);
}

// Round 4
// 21445.789 us; speedup vs baseline: 3.7809x; 1.1328x over previous
//
#include <hip/hip_runtime.h>

// Problem constants (fixed by harness inputs)
#define BATCH 128
#define NSAMP 4
#define BN    512        // BATCH*NSAMP
#define HID   512
#define EMBD  512
#define VOC   512
#define TLEN  100
#define MLEN  256
#define NGATE 2048       // 4*HID

#define NPART 8          // split-K partials for q/logits GEMMs (bit-exact contract)

// output flat offsets (FLOAT32 elements)
#define O_ZID     0L
#define O_ZSTATES 51200L
#define O_ZLP     26265600L
#define O_STEP    26266112L
#define O_ENT     26317312L
#define O_TOTAL   26317313L

// workspace offsets (floats) inside g_ws
#define OFF_H    0L          // [512][1024]
#define OFF_C    524288L     // [512][1024]
#define OFF_X    1048576L    // [512][512]
#define OFF_G    1310720L    // [512][2048] final gates (single buffer now)
#define OFF_Q    9699328L    // 8 x [512][512] q partials
#define OFF_CTX  11796480L   // [512][512]
#define OFF_O2   12058624L   // 8 x [512][512] cproj partials
#define OFF_LG   14155776L   // 8 x [512][512] logit partials
#define OFF_YR   16252928L   // [512][512]
#define OFF_BG   16515072L   // [2][2048]
#define OFF_ENT  16519168L   // [128]
#define OFF_SLP  16519296L   // [100*512]
#define OFF_O2R  16570496L   // [512][512] reduced out2
#define WS_FLOATS 16832640L

#define SPSTRIDE 262144L     // 512*512 small-partial stride

__device__ float g_ws[WS_FLOATS];
__device__ int   g_ids[TLEN * BN];

// ---------------- threefry2x32 (JAX-exact, 20 rounds) ----------------
__device__ __forceinline__ unsigned rotl32(unsigned x, int r) {
  return (x << r) | (x >> (32 - r));
}
__device__ __forceinline__ void threefry2x32(unsigned k0, unsigned k1,
                                             unsigned& x0, unsigned& x1) {
  unsigned k2 = k0 ^ k1 ^ 0x1BD11BDAu;
#define TF_R(r) { x0 += x1; x1 = rotl32(x1, r); x1 ^= x0; }
  x0 += k0; x1 += k1;
  TF_R(13) TF_R(15) TF_R(26) TF_R(6)
  x0 += k1; x1 += k2 + 1u;
  TF_R(17) TF_R(29) TF_R(16) TF_R(24)
  x0 += k2; x1 += k0 + 2u;
  TF_R(13) TF_R(15) TF_R(26) TF_R(6)
  x0 += k0; x1 += k1 + 3u;
  TF_R(17) TF_R(29) TF_R(16) TF_R(24)
  x0 += k1; x1 += k2 + 4u;
  TF_R(13) TF_R(15) TF_R(26) TF_R(6)
  x0 += k2; x1 += k0 + 5u;
#undef TF_R
}

__device__ __forceinline__ float gumbel_from_bits(unsigned bits) {
  unsigned fb = (bits >> 9) | 0x3F800000u;
  float f = __uint_as_float(fb) - 1.0f;          // [0,1)
  const float TINY = 1.17549435e-38f;
  float u = fmaxf(f + TINY, TINY);
  return -logf(-logf(u));
}

// XLA-style logistic: 0.5 + 0.5*tanh(0.5*x)
__device__ __forceinline__ float sigf(float x) {
  return 0.5f + 0.5f * tanhf(0.5f * x);
}

__device__ __forceinline__ float4 add4(float4 a, float4 b) {
  a.x += b.x; a.y += b.y; a.z += b.z; a.w += b.w; return a;
}

// ---------------- gates_fused: 8 waves = 8 k-chunks of the old split-K, ---------
// chunk GEMM identical to gemmsk, then in-LDS p-ascending reduction + bias.
// Writes the FINAL gate matrix [512][2048] (no partial round-trip).
__global__ __launch_bounds__(512) void gates_fused(
    long offA1, int lda1, const float* __restrict__ B1, int K1,
    long offA2, int lda2, const float* __restrict__ B2,
    long biasOff, long offC)
{
  __shared__ float S[16384];     // 64 KiB: 8 waves x (As 1024 | Bs 1024)
  const int tid  = threadIdx.x;
  const int w    = tid >> 6;     // wave = k-chunk index (old blockIdx.z)
  const int lane = tid & 63;
  const int tm = lane >> 3, tn = lane & 7;
  const int m0 = blockIdx.y * 64;
  const int n0 = blockIdx.x * 64;
  float* As = S + w * 2048;
  float* Bs = As + 1024;

  int kbase = w * 128;           // Kc = 128
  const float* A; const float* B; int lda;
  if (kbase < K1) { A = g_ws + offA1; lda = lda1; B = B1; }
  else            { A = g_ws + offA2; lda = lda2; B = B2; kbase -= K1; }

  float acc[8][8];
#pragma unroll
  for (int i = 0; i < 8; ++i)
#pragma unroll
    for (int j = 0; j < 8; ++j) acc[i][j] = 0.f;

  for (int k0 = 0; k0 < 128; k0 += 16) {
    const int kg = kbase + k0;
    const float4* q4 = (const float4*)(A + (size_t)(m0 + lane) * lda + kg);
    float4 a0 = q4[0], a1 = q4[1], a2 = q4[2], a3 = q4[3];
    const float4* pb = (const float4*)(B + (size_t)(n0 + lane) * 512 + kg);
    float4 b0 = pb[0], b1 = pb[1], b2 = pb[2], b3 = pb[3];

    __syncthreads();
    As[ 0*64+lane]=a0.x; As[ 1*64+lane]=a0.y; As[ 2*64+lane]=a0.z; As[ 3*64+lane]=a0.w;
    As[ 4*64+lane]=a1.x; As[ 5*64+lane]=a1.y; As[ 6*64+lane]=a1.z; As[ 7*64+lane]=a1.w;
    As[ 8*64+lane]=a2.x; As[ 9*64+lane]=a2.y; As[10*64+lane]=a2.z; As[11*64+lane]=a2.w;
    As[12*64+lane]=a3.x; As[13*64+lane]=a3.y; As[14*64+lane]=a3.z; As[15*64+lane]=a3.w;
    Bs[ 0*64+lane]=b0.x; Bs[ 1*64+lane]=b0.y; Bs[ 2*64+lane]=b0.z; Bs[ 3*64+lane]=b0.w;
    Bs[ 4*64+lane]=b1.x; Bs[ 5*64+lane]=b1.y; Bs[ 6*64+lane]=b1.z; Bs[ 7*64+lane]=b1.w;
    Bs[ 8*64+lane]=b2.x; Bs[ 9*64+lane]=b2.y; Bs[10*64+lane]=b2.z; Bs[11*64+lane]=b2.w;
    Bs[12*64+lane]=b3.x; Bs[13*64+lane]=b3.y; Bs[14*64+lane]=b3.z; Bs[15*64+lane]=b3.w;
    __syncthreads();

#pragma unroll
    for (int k = 0; k < 16; ++k) {
      float av[8], bv[8];
      *(float4*)&av[0] = *(const float4*)&As[k*64 + tm*8];
      *(float4*)&av[4] = *(const float4*)&As[k*64 + tm*8 + 4];
      *(float4*)&bv[0] = *(const float4*)&Bs[k*64 + tn*8];
      *(float4*)&bv[4] = *(const float4*)&Bs[k*64 + tn*8 + 4];
#pragma unroll
      for (int i = 0; i < 8; ++i)
#pragma unroll
        for (int j = 0; j < 8; ++j)
          acc[i][j] += av[i] * bv[j];
    }
  }

  // in-LDS reduction over the 8 chunks, 4 row-slices of 16 rows each.
  // total = ((chunk0 + bias) + chunk1) + ... + chunk7  — exact old order.
  const float* bias = g_ws + biasOff;
  float* red = S;                       // reuse first 32 KiB (waves 0..3 slices)
  for (int s = 0; s < 4; ++s) {
    __syncthreads();
    if ((tm >> 1) == s) {               // this thread's rows are in slice s
      const int rb = (tm & 1) * 8;
#pragma unroll
      for (int i = 0; i < 8; ++i)
#pragma unroll
        for (int j = 0; j < 8; ++j)
          red[w * 1024 + (rb + i) * 64 + tn * 8 + j] = acc[i][j];
    }
    __syncthreads();
    for (int u = tid; u < 1024; u += 512) {
      const int r = u >> 6, c = u & 63;
      float t = red[u] + bias[n0 + c];  // P0 = chunk0 + bias (old kp==0 store)
#pragma unroll
      for (int p = 1; p < 8; ++p) t += red[p * 1024 + u];
      g_ws[offC + (size_t)(m0 + s * 16 + r) * 2048 + n0 + c] = t;
    }
  }
}

// ---------------- split-K fp32 GEMM: 64 threads, 64x64 tile, 8x8 micro, BK=16 ----
// (verbatim baseline — q / cproj / logits)
__global__ __launch_bounds__(64) void gemmsk(
    long offA1, int lda1, int P1, long strideP1,
    const float* __restrict__ B1, int ldb1, int K1,
    long offA2, int lda2,
    const float* __restrict__ B2, int ldb2,
    const float* __restrict__ biasExt, long biasOff,
    long offC, int ldc, int Kc)
{
  __shared__ float As[16][64];
  __shared__ float Bs[16][64];
  const int t  = threadIdx.x;
  const int tm = t >> 3;         // 0..7
  const int tn = t & 7;          // 0..7
  const int m0 = blockIdx.y * 64;
  const int n0 = blockIdx.x * 64;
  const int kp = blockIdx.z;

  int kbase = kp * Kc;
  const float* A; const float* B; int lda, ldb, P; long strideP;
  if (kbase < K1) {
    A = g_ws + offA1; B = B1; lda = lda1; ldb = ldb1; P = P1; strideP = strideP1;
  } else {
    A = g_ws + offA2; B = B2; lda = lda2; ldb = ldb2; P = 1; strideP = 0;
    kbase -= K1;
  }

  float acc[8][8];
#pragma unroll
  for (int i = 0; i < 8; ++i)
#pragma unroll
    for (int j = 0; j < 8; ++j) acc[i][j] = 0.f;

  for (int k0 = 0; k0 < Kc; k0 += 16) {
    const int kg = kbase + k0;
    const float* pa = A + (size_t)(m0 + t) * lda + kg;
    float4 a0, a1, a2, a3;
    {
      const float4* q4 = (const float4*)pa;
      a0 = q4[0]; a1 = q4[1]; a2 = q4[2]; a3 = q4[3];
      for (int p = 1; p < P; ++p) {
        const float4* r4 = (const float4*)(pa + (size_t)p * strideP);
        a0 = add4(a0, r4[0]); a1 = add4(a1, r4[1]);
        a2 = add4(a2, r4[2]); a3 = add4(a3, r4[3]);
      }
    }
    const float4* pb = (const float4*)(B + (size_t)(n0 + t) * ldb + kg);
    float4 b0 = pb[0], b1 = pb[1], b2 = pb[2], b3 = pb[3];

    __syncthreads();
    As[ 0][t] = a0.x; As[ 1][t] = a0.y; As[ 2][t] = a0.z; As[ 3][t] = a0.w;
    As[ 4][t] = a1.x; As[ 5][t] = a1.y; As[ 6][t] = a1.z; As[ 7][t] = a1.w;
    As[ 8][t] = a2.x; As[ 9][t] = a2.y; As[10][t] = a2.z; As[11][t] = a2.w;
    As[12][t] = a3.x; As[13][t] = a3.y; As[14][t] = a3.z; As[15][t] = a3.w;
    Bs[ 0][t] = b0.x; Bs[ 1][t] = b0.y; Bs[ 2][t] = b0.z; Bs[ 3][t] = b0.w;
    Bs[ 4][t] = b1.x; Bs[ 5][t] = b1.y; Bs[ 6][t] = b1.z; Bs[ 7][t] = b1.w;
    Bs[ 8][t] = b2.x; Bs[ 9][t] = b2.y; Bs[10][t] = b2.z; Bs[11][t] = b2.w;
    Bs[12][t] = b3.x; Bs[13][t] = b3.y; Bs[14][t] = b3.z; Bs[15][t] = b3.w;
    __syncthreads();

#pragma unroll
    for (int k = 0; k < 16; ++k) {
      float av[8], bv[8];
      *(float4*)&av[0] = *(const float4*)&As[k][tm * 8];
      *(float4*)&av[4] = *(const float4*)&As[k][tm * 8 + 4];
      *(float4*)&bv[0] = *(const float4*)&Bs[k][tn * 8];
      *(float4*)&bv[4] = *(const float4*)&Bs[k][tn * 8 + 4];
#pragma unroll
      for (int i = 0; i < 8; ++i)
#pragma unroll
        for (int j = 0; j < 8; ++j)
          acc[i][j] += av[i] * bv[j];
    }
  }

  const int Mtot = gridDim.y * 64;
  float* C = g_ws + offC + (size_t)kp * (size_t)Mtot * ldc;
  const float* bias = nullptr;
  if (kp == 0)
    bias = biasExt ? biasExt : (biasOff >= 0 ? g_ws + biasOff : nullptr);
#pragma unroll
  for (int i = 0; i < 8; ++i) {
    const int row = m0 + tm * 8 + i;
    const int col = n0 + tn * 8;
    float4 o0, o1;
    o0.x = acc[i][0]; o0.y = acc[i][1]; o0.z = acc[i][2]; o0.w = acc[i][3];
    o1.x = acc[i][4]; o1.y = acc[i][5]; o1.z = acc[i][6]; o1.w = acc[i][7];
    if (bias) {
      o0.x += bias[col];     o0.y += bias[col + 1];
      o0.z += bias[col + 2]; o0.w += bias[col + 3];
      o1.x += bias[col + 4]; o1.y += bias[col + 5];
      o1.z += bias[col + 6]; o1.w += bias[col + 7];
    }
    *(float4*)(C + (size_t)row * ldc + col)     = o0;
    *(float4*)(C + (size_t)row * ldc + col + 4) = o1;
  }
}

// ---------------- old single-pass GEMM (init h0/c0 only) ----------------
__global__ __launch_bounds__(256) void gemm2(
    long offA1, int lda1,
    const float* __restrict__ B1, int ldb1, int K1,
    long offA2, int lda2,
    const float* __restrict__ B2, int ldb2, int K2,
    const float* __restrict__ biasExt, long biasOff,
    long offC, int ldc)
{
  __shared__ float As[16][68];
  __shared__ float Bs[16][68];
  const int tid = threadIdx.x;
  const int tx  = tid & 15;
  const int ty  = tid >> 4;
  const int ldr = tid >> 2;
  const int ldk = (tid & 3) << 2;
  const int m0 = blockIdx.y * 64;
  const int n0 = blockIdx.x * 64;
  float acc[4][4] = {{0.f}};

  for (int seg = 0; seg < 2; ++seg) {
    const float* A = g_ws + (seg ? offA2 : offA1);
    const float* B = seg ? B2 : B1;
    const int lda = seg ? lda2 : lda1;
    const int ldb = seg ? ldb2 : ldb1;
    const int K   = seg ? K2  : K1;
    for (int k0 = 0; k0 < K; k0 += 16) {
      float4 av = *(const float4*)(A + (size_t)(m0 + ldr) * lda + k0 + ldk);
      float4 bv = *(const float4*)(B + (size_t)(n0 + ldr) * ldb + k0 + ldk);
      __syncthreads();
      As[ldk + 0][ldr] = av.x; As[ldk + 1][ldr] = av.y;
      As[ldk + 2][ldr] = av.z; As[ldk + 3][ldr] = av.w;
      Bs[ldk + 0][ldr] = bv.x; Bs[ldk + 1][ldr] = bv.y;
      Bs[ldk + 2][ldr] = bv.z; Bs[ldk + 3][ldr] = bv.w;
      __syncthreads();
#pragma unroll
      for (int k = 0; k < 16; ++k) {
        float4 a = *(const float4*)&As[k][ty * 4];
        float4 b = *(const float4*)&Bs[k][tx * 4];
        acc[0][0] += a.x * b.x; acc[0][1] += a.x * b.y; acc[0][2] += a.x * b.z; acc[0][3] += a.x * b.w;
        acc[1][0] += a.y * b.x; acc[1][1] += a.y * b.y; acc[1][2] += a.y * b.z; acc[1][3] += a.y * b.w;
        acc[2][0] += a.z * b.x; acc[2][1] += a.z * b.y; acc[2][2] += a.z * b.z; acc[2][3] += a.z * b.w;
        acc[3][0] += a.w * b.x; acc[3][1] += a.w * b.y; acc[3][2] += a.w * b.z; acc[3][3] += a.w * b.w;
      }
    }
  }
  const float* bias = biasExt ? biasExt : (biasOff >= 0 ? g_ws + biasOff : nullptr);
  float* C = g_ws + offC;
#pragma unroll
  for (int i = 0; i < 4; ++i) {
    int row = m0 + ty * 4 + i;
    int col = n0 + tx * 4;
    float4 o;
    o.x = acc[i][0]; o.y = acc[i][1]; o.z = acc[i][2]; o.w = acc[i][3];
    if (bias) {
      o.x += bias[col]; o.y += bias[col + 1]; o.z += bias[col + 2]; o.w += bias[col + 3];
    }
    *(float4*)(C + (size_t)row * ldc + col) = o;
  }
}

// ---------------- LSTM cell elementwise; reads SINGLE gate buffer ----------------
__global__ __launch_bounds__(256) void lstm_cell(long hoff, long coff)
{
  int idx = blockIdx.x * 256 + threadIdx.x;   // 0..262143
  int r = idx >> 9, j = idx & 511;
  const float* gr = g_ws + OFF_G + (size_t)r * NGATE;
  float gi = gr[j], gf = gr[512 + j], gg = gr[1024 + j], go = gr[1536 + j];
  float* h = g_ws + hoff;
  float* c = g_ws + coff;
  float cold = c[(size_t)r * 1024 + j];
  float cn = sigf(gf) * cold + sigf(gi) * tanhf(gg);
  float hn = sigf(go) * tanhf(cn);
  c[(size_t)r * 1024 + j] = cn;
  h[(size_t)r * 1024 + j] = hn;
}

// ---------------- o2_reduce: collapse 8 cproj partials (p-ascending, exact) -----
__global__ __launch_bounds__(256) void o2_reduce()
{
  int e = blockIdx.x * 256 + threadIdx.x;     // 1024 blocks -> 262144
  float t = g_ws[OFF_O2 + e];
#pragma unroll
  for (int p = 1; p < 8; ++p) t += g_ws[OFF_O2 + (size_t)p * SPSTRIDE + e];
  g_ws[OFF_O2R + e] = t;
}

// ---------------- attention: block b handles 4 samples sharing kv[b]; sums q partials ----------------
__global__ __launch_bounds__(256) void attn_kernel(
    const float* __restrict__ kv,
    const void*  __restrict__ kvm_raw)
{
  __shared__ float qs[4][512];
  __shared__ float sc[4][256];
  const int b = blockIdx.x;
  const int tid = threadIdx.x;
  const int lane = tid & 63, wave = tid >> 6;
  float* ctx = g_ws + OFF_CTX;
  const float* kvb = kv + (size_t)b * MLEN * HID;
  const unsigned* w32 = (const unsigned*)kvm_raw;
  const unsigned char* u8 = (const unsigned char*)kvm_raw;
  const bool u8mode = (w32[0] == 0x01010101u);
#pragma unroll
  for (int s = 0; s < 4; ++s) {
    float q0 = 0.f, q1 = 0.f;
    const size_t base = (size_t)(b * 4 + s) * HID + tid;
#pragma unroll
    for (int p = 0; p < NPART; ++p) {
      q0 += g_ws[OFF_Q + (size_t)p * SPSTRIDE + base];
      q1 += g_ws[OFF_Q + (size_t)p * SPSTRIDE + base + 256];
    }
    qs[s][tid] = q0; qs[s][tid + 256] = q1;
  }
  __syncthreads();
  // pass 1: scores
  for (int m = wave; m < MLEN; m += 4) {
    const float* kr = kvb + (size_t)m * HID;
    float a0 = 0.f, a1 = 0.f, a2 = 0.f, a3 = 0.f;
    for (int d = lane; d < HID; d += 64) {
      float kvv = kr[d];
      a0 += qs[0][d] * kvv; a1 += qs[1][d] * kvv;
      a2 += qs[2][d] * kvv; a3 += qs[3][d] * kvv;
    }
#pragma unroll
    for (int off = 32; off > 0; off >>= 1) {
      a0 += __shfl_down(a0, off); a1 += __shfl_down(a1, off);
      a2 += __shfl_down(a2, off); a3 += __shfl_down(a3, off);
    }
    if (lane == 0) {
      bool on = u8mode ? (u8[b * MLEN + m] != 0) : (w32[b * MLEN + m] != 0u);
      float madd = on ? 0.0f : -1e9f;
      sc[0][m] = a0 + madd; sc[1][m] = a1 + madd;
      sc[2][m] = a2 + madd; sc[3][m] = a3 + madd;
    }
  }
  __syncthreads();
  // softmax (wave s handles sample s)
  {
    const int s = wave;
    float mx = -3.4e38f;
    for (int m = lane; m < MLEN; m += 64) mx = fmaxf(mx, sc[s][m]);
#pragma unroll
    for (int off = 32; off > 0; off >>= 1) mx = fmaxf(mx, __shfl_xor(mx, off));
    float sum = 0.f;
    for (int m = lane; m < MLEN; m += 64) {
      float e = expf(sc[s][m] - mx);
      sc[s][m] = e; sum += e;
    }
#pragma unroll
    for (int off = 32; off > 0; off >>= 1) sum += __shfl_xor(sum, off);
    for (int m = lane; m < MLEN; m += 64) sc[s][m] = sc[s][m] / sum;
  }
  __syncthreads();
  // pass 2: ctx
  float c00=0,c01=0,c10=0,c11=0,c20=0,c21=0,c30=0,c31=0;
  for (int m = 0; m < MLEN; ++m) {
    float k0v = kvb[(size_t)m * HID + tid];
    float k1v = kvb[(size_t)m * HID + tid + 256];
    float p0 = sc[0][m], p1 = sc[1][m], p2 = sc[2][m], p3 = sc[3][m];
    c00 += p0 * k0v; c01 += p0 * k1v;
    c10 += p1 * k0v; c11 += p1 * k1v;
    c20 += p2 * k0v; c21 += p2 * k1v;
    c30 += p3 * k0v; c31 += p3 * k1v;
  }
  ctx[(size_t)(b * 4 + 0) * HID + tid] = c00; ctx[(size_t)(b * 4 + 0) * HID + tid + 256] = c01;
  ctx[(size_t)(b * 4 + 1) * HID + tid] = c10; ctx[(size_t)(b * 4 + 1) * HID + tid + 256] = c11;
  ctx[(size_t)(b * 4 + 2) * HID + tid] = c20; ctx[(size_t)(b * 4 + 2) * HID + tid + 256] = c21;
  ctx[(size_t)(b * 4 + 3) * HID + tid] = c30; ctx[(size_t)(b * 4 + 3) * HID + tid + 256] = c31;
}

// ---------------- sampling; sums logit partials ----------------
__global__ __launch_bounds__(256) void sample_step(
    const float* __restrict__ emb, int t)
{
  __shared__ float rz[256];
  __shared__ int   ri[256];
  __shared__ float rl[256];
  const int row = blockIdx.x;
  const int tid = threadIdx.x;
  float* xbuf = g_ws + OFF_X;

  unsigned fk0 = 0u, fk1 = (unsigned)t;
  threefry2x32(0u, 42u, fk0, fk1);

  float l[2], g[2];
#pragma unroll
  for (int j = 0; j < 2; ++j) {
    int v = tid + j * 256;
    unsigned c0 = 0u, c1 = (unsigned)(row * VOC + v);
    threefry2x32(fk0, fk1, c0, c1);
    g[j] = gumbel_from_bits(c0 ^ c1);
    float lv = 0.f;
    const size_t base = (size_t)row * VOC + v;
#pragma unroll
    for (int p = 0; p < NPART; ++p)
      lv += g_ws[OFF_LG + (size_t)p * SPSTRIDE + base];
    l[j] = lv;
  }

  float z0 = l[0] + g[0], z1 = l[1] + g[1];
  float bz; int bi; float bl;
  if (z1 > z0) { bz = z1; bi = tid + 256; bl = l[1]; }
  else         { bz = z0; bi = tid;       bl = l[0]; }
  rz[tid] = bz; ri[tid] = bi; rl[tid] = bl;
  __syncthreads();
  for (int s = 128; s > 0; s >>= 1) {
    if (tid < s) {
      float oz = rz[tid + s]; int oi = ri[tid + s];
      if (oz > rz[tid] || (oz == rz[tid] && oi < ri[tid])) {
        rz[tid] = oz; ri[tid] = oi; rl[tid] = rl[tid + s];
      }
    }
    __syncthreads();
  }
  const int idx = ri[0];
  const float l_at = rl[0];
  __syncthreads();

  rz[tid] = fmaxf(l[0], l[1]);
  __syncthreads();
  for (int s = 128; s > 0; s >>= 1) {
    if (tid < s) rz[tid] = fmaxf(rz[tid], rz[tid + s]);
    __syncthreads();
  }
  const float m = rz[0];
  __syncthreads();

  float d0 = l[0] - m, d1 = l[1] - m;
  float e0 = expf(d0), e1 = expf(d1);
  rz[tid] = e0 + e1;
  rl[tid] = e0 * d0 + e1 * d1;
  __syncthreads();
  for (int s = 128; s > 0; s >>= 1) {
    if (tid < s) { rz[tid] += rz[tid + s]; rl[tid] += rl[tid + s]; }
    __syncthreads();
  }
  if (tid == 0) {
    float S = rz[0], W = rl[0];
    float logS = logf(S);
    g_ids[t * BN + row] = idx;
    g_ws[OFF_SLP + t * BN + row] = (l_at - m) - logS;
    atomicAdd(&g_ws[OFF_ENT + t], logS - W / S);
  }
  const float* er = emb + (size_t)idx * EMBD;
  xbuf[(size_t)row * EMBD + tid]       = er[tid];
  xbuf[(size_t)row * EMBD + tid + 256] = er[tid + 256];
}

// ---------------- init ----------------
__global__ __launch_bounds__(256) void init_misc(
    const float* __restrict__ y, const float* __restrict__ emb,
    const float* __restrict__ b_ih, const float* __restrict__ b_hh)
{
  int gid = blockIdx.x * 256 + threadIdx.x;
  int r = gid >> 9, col = gid & 511;
  g_ws[OFF_YR + gid] = y[(size_t)(r >> 2) * HID + col];
  g_ws[OFF_X + gid]  = emb[(size_t)(VOC - 1) * EMBD + col];
  if (gid < 2 * NGATE) g_ws[OFF_BG + gid] = b_ih[gid] + b_hh[gid];
  if (gid < 128) g_ws[OFF_ENT + gid] = 0.0f;
}

// ---------------- SINGLE output writer (f32) ----------------
__global__ __launch_bounds__(256) void write_out(
    const float* __restrict__ emb, const float* __restrict__ zmask,
    float* __restrict__ out)
{
  long i = (long)blockIdx.x * 256 + threadIdx.x;
  const long stride = (long)gridDim.x * 256;
  for (; i < O_TOTAL; i += stride) {
    float v;
    if (i < O_ZSTATES) {
      int bs = (int)(i / TLEN), t = (int)(i % TLEN);
      v = (float)g_ids[t * BN + bs];
    } else if (i < O_ZLP) {
      long j = i - O_ZSTATES;
      int e = (int)(j & 511);
      int bst = (int)(j >> 9);
      int bs = bst / TLEN, t = bst % TLEN;
      v = emb[(size_t)g_ids[t * BN + bs] * EMBD + e];
    } else if (i < O_STEP) {
      int bs = (int)(i - O_ZLP);
      int b = bs >> 2;
      float acc = 0.f;
      for (int t = 0; t < TLEN; ++t)
        acc += g_ws[OFF_SLP + t * BN + bs] * zmask[b * TLEN + t];
      v = acc;
    } else if (i < O_ENT) {
      long j = i - O_STEP;
      int bs = (int)(j / TLEN), t = (int)(j % TLEN);
      v = g_ws[OFF_SLP + t * BN + bs];
    } else {
      float e = 0.f;
      for (int t = 0; t < TLEN; ++t) e += g_ws[OFF_ENT + t];
      v = e / (float)(BN * TLEN);
    }
    out[i] = v;
  }
}

// ---------------- host ----------------
extern "C" void kernel_launch(void* const* d_in, const int* in_sizes, int n_in,
                              void* d_out, int out_size, void* d_ws, size_t ws_size,
                              hipStream_t stream) {
  (void)in_sizes; (void)n_in; (void)out_size; (void)d_ws; (void)ws_size;
  const float* y       = (const float*)d_in[0];
  const float* kv      = (const float*)d_in[1];
  const void*  kvm     = (const void*)d_in[2];
  const float* zmask   = (const float*)d_in[3];
  const float* emb     = (const float*)d_in[4];
  const float* W_h0    = (const float*)d_in[5];
  const float* b_h0    = (const float*)d_in[6];
  const float* W_c0    = (const float*)d_in[7];
  const float* b_c0    = (const float*)d_in[8];
  const float* W_ih    = (const float*)d_in[9];
  const float* W_hh    = (const float*)d_in[10];
  const float* b_ih    = (const float*)d_in[11];
  const float* b_hh    = (const float*)d_in[12];
  const float* W_attn  = (const float*)d_in[13];
  const float* W_cproj = (const float*)d_in[14];
  const float* b_cproj = (const float*)d_in[15];
  const float* W_out   = (const float*)d_in[16];
  const float* b_out   = (const float*)d_in[17];
  float* out = (float*)d_out;

  init_misc<<<1024, 256, 0, stream>>>(y, emb, b_ih, b_hh);

  // init h0 / c0 (outside loop)
  dim3 g_init(1024 / 64, 512 / 64);
  gemm2<<<g_init, 256, 0, stream>>>(OFF_YR, 512, W_h0, 512, 512,
                                    0L, 0, nullptr, 0, 0, b_h0, -1L, OFF_H, 1024);
  gemm2<<<g_init, 256, 0, stream>>>(OFF_YR, 512, W_c0, 512, 512,
                                    0L, 0, nullptr, 0, 0, b_c0, -1L, OFF_C, 1024);

  dim3 g_gf(2048 / 64, 512 / 64);             // 32 n-tiles x 8 m-tiles = 256 blocks
  dim3 g_sq(512 / 64, 512 / 64, NPART);
  const size_t WL = (size_t)NGATE * HID;

  for (int t = 0; t < TLEN; ++t) {
    // layer 0 gates (single fused split-K, writes final gate matrix)
    gates_fused<<<g_gf, 512, 0, stream>>>(OFF_X, 512, W_ih, 512,
                                          OFF_H, 1024, W_hh,
                                          OFF_BG, OFF_G);
    lstm_cell<<<1024, 256, 0, stream>>>(OFF_H, OFF_C);
    // layer 1 gates
    gates_fused<<<g_gf, 512, 0, stream>>>(OFF_H, 1024, W_ih + WL, 512,
                                          OFF_H + 512, 1024, W_hh + WL,
                                          OFF_BG + NGATE, OFF_G);
    lstm_cell<<<1024, 256, 0, stream>>>(OFF_H + 512, OFF_C + 512);
    // q = h1 @ W_attn^T   (Kc=64 over K=512, 8 partials summed in attn)
    gemmsk<<<g_sq, 64, 0, stream>>>(OFF_H + 512, 1024, 1, 0L, W_attn, 512, 512,
                                    0L, 0, nullptr, 0,
                                    nullptr, -1L, OFF_Q, 512, 64);
    attn_kernel<<<128, 256, 0, stream>>>(kv, kvm);
    // out2 = [h1|ctx] @ W_cproj^T + b  (Kc=128 over K=1024, 8 partials)
    gemmsk<<<g_sq, 64, 0, stream>>>(OFF_H + 512, 1024, 1, 0L, W_cproj, 1024, 512,
                                    OFF_CTX, 512, W_cproj + 512, 1024,
                                    b_cproj, -1L, OFF_O2, 512, 128);
    // collapse out2 partials once (saves 8x re-read in logits)
    o2_reduce<<<1024, 256, 0, stream>>>();
    // logits = out2 @ W_out^T + b  (reduced A, P=1; Kc=64)
    gemmsk<<<g_sq, 64, 0, stream>>>(OFF_O2R, 512, 1, 0L, W_out, 512, 512,
                                    0L, 0, nullptr, 0,
                                    b_out, -1L, OFF_LG, 512, 64);
    sample_step<<<512, 256, 0, stream>>>(emb, t);
  }

  int wblocks = (int)((O_TOTAL + 255L) / 256L);
  write_out<<<wblocks, 256, 0, stream>>>(emb, zmask, out);
}